// Round 1
// baseline (587.281 us; speedup 1.0000x reference)
//
#include <hip/hip_runtime.h>
#include <hip/hip_bf16.h>

typedef unsigned short u16;
typedef __attribute__((ext_vector_type(8))) short bf8;   // 8 bf16 (raw bits, 4 VGPRs)
typedef __attribute__((ext_vector_type(4))) float f32x4;

#define CH_ 512
#define NSP 1024      // 32*32 spatial
#define NB 8
#define CONDDIM 1280
#define NGROUP 64     // 512/8
#define HEADS_ 8
#define HD 64         // head dim

__device__ __forceinline__ u16 f2bf(float f) {
  union { float f; unsigned u; } v; v.f = f;
  unsigned u = v.u;
  return (u16)((u + 0x7fffu + ((u >> 16) & 1u)) >> 16);   // RNE
}

__device__ __forceinline__ f32x4 mfma_bf16(bf8 a, bf8 b, f32x4 c) {
  return __builtin_amdgcn_mfma_f32_16x16x32_bf16(a, b, c, 0, 0, 0);
}

// ---------------- pack / transpose kernels ----------------

// x: NCHW f32 -> xb: NHWC bf16
__global__ __launch_bounds__(1024) void pack_x_kernel(const float* __restrict__ x, u16* __restrict__ xb) {
  __shared__ float t[32][33];
  int b = blockIdx.z;
  int c0 = blockIdx.y * 32, p0 = blockIdx.x * 32;
  int tx = threadIdx.x & 31, ty = threadIdx.x >> 5;
  t[ty][tx] = x[((size_t)b * CH_ + c0 + ty) * NSP + p0 + tx];
  __syncthreads();
  xb[((size_t)b * NSP + p0 + ty) * CH_ + c0 + tx] = f2bf(t[tx][ty]);
}

// NHWC f32 -> NCHW f32 (final output)
__global__ __launch_bounds__(1024) void transpose_out_kernel(const float* __restrict__ in, float* __restrict__ out) {
  __shared__ float t[32][33];
  int b = blockIdx.z;
  int c0 = blockIdx.y * 32, p0 = blockIdx.x * 32;
  int tx = threadIdx.x & 31, ty = threadIdx.x >> 5;
  t[ty][tx] = in[((size_t)b * NSP + p0 + ty) * CH_ + c0 + tx];
  __syncthreads();
  out[((size_t)b * CH_ + c0 + ty) * NSP + p0 + tx] = t[tx][ty];
}

// 3x3 weights [co][ci][3][3] f32 -> packed [t][ci/8][co][8] bf16
__global__ __launch_bounds__(256) void pack_w3_kernel(const float* __restrict__ w, u16* __restrict__ wp) {
  int id = blockIdx.x * 256 + threadIdx.x;        // (t, cib, co)
  if (id >= 9 * 64 * CH_) return;
  int co = id & (CH_ - 1);
  int cib = (id >> 9) & 63;
  int t = id >> 15;
  int dy = t / 3, dx = t % 3;
  bf8 v;
#pragma unroll
  for (int j = 0; j < 8; j++) {
    int ci = cib * 8 + j;
    v[j] = (short)f2bf(w[(((size_t)co * CH_ + ci) * 3 + dy) * 3 + dx]);
  }
  *(bf8*)(wp + ((size_t)(t * 64 + cib) * CH_ + co) * 8) = v;
}

// 1x1 weights [co][ci] f32 -> packed [ci/8][co][8] bf16
__global__ __launch_bounds__(256) void pack_w1_kernel(const float* __restrict__ w, u16* __restrict__ wp) {
  int id = blockIdx.x * 256 + threadIdx.x;        // (cib, co)
  if (id >= 64 * CH_) return;
  int co = id & (CH_ - 1);
  int cib = id >> 9;
  bf8 v;
#pragma unroll
  for (int j = 0; j < 8; j++) v[j] = (short)f2bf(w[(size_t)co * CH_ + cib * 8 + j]);
  *(bf8*)(wp + ((size_t)cib * CH_ + co) * 8) = v;
}

// cond[b][c] = conditioning[b] . cpw[c] + cpb[c]   (f32)
__global__ __launch_bounds__(256) void cond_kernel(const float* __restrict__ cd, const float* __restrict__ cpw,
                                                   const float* __restrict__ cpb, float* __restrict__ cond) {
  int b = blockIdx.y;
  int c = blockIdx.x * 4 + (threadIdx.x >> 6);
  int lane = threadIdx.x & 63;
  const float* wrow = cpw + (size_t)c * CONDDIM;
  const float* crow = cd + (size_t)b * CONDDIM;
  float s = 0.f;
  for (int i = lane; i < CONDDIM; i += 64) s += crow[i] * wrow[i];
#pragma unroll
  for (int m = 32; m > 0; m >>= 1) s += __shfl_xor(s, m, 64);
  if (lane == 0) cond[b * CH_ + c] = s + cpb[c];
}

// ---------------- implicit-GEMM conv (1x1 or 3x3 pad=1) ----------------
// in:  bf16 NHWC [B][1024][512]
// wp:  bf16 packed [TAPS][64][512][8]
// tile: 128 p x 64 co, 4 waves (2x2), each wave 64p x 32co
// EPI: 0 = f32 NHWC out (+bias); 1 = bf16 NHWC out (+bias); 2 = f32 NHWC out (+bias+addf)
template <int TAPS, int EPI>
__global__ __launch_bounds__(256) void conv_gemm_kernel(
    const u16* __restrict__ in, const u16* __restrict__ wp, const float* __restrict__ bias,
    float* __restrict__ outf, u16* __restrict__ outb, const float* __restrict__ addf) {
  int b = blockIdx.z;
  int co0 = blockIdx.y * 64;
  int p0 = blockIdx.x * 128;
  int tid = threadIdx.x;
  int lane = tid & 63, wid = tid >> 6;
  int wr = wid >> 1, wc = wid & 1;
  int l15 = lane & 15, lhi = lane >> 4;

  f32x4 acc[4][2];
#pragma unroll
  for (int m = 0; m < 4; m++)
#pragma unroll
    for (int n = 0; n < 2; n++) acc[m][n] = {0.f, 0.f, 0.f, 0.f};

  const u16* inb = in + (size_t)b * NSP * CH_;
  int pm[4];
#pragma unroll
  for (int m = 0; m < 4; m++) pm[m] = p0 + wr * 64 + m * 16 + l15;

  const bf8 zero8 = {0, 0, 0, 0, 0, 0, 0, 0};

  for (int t = 0; t < TAPS; ++t) {
    int dy = (TAPS == 9) ? (t / 3 - 1) : 0;
    int dx = (TAPS == 9) ? (t % 3 - 1) : 0;
    int srcp[4]; bool val[4];
#pragma unroll
    for (int m = 0; m < 4; m++) {
      int y = pm[m] >> 5, x = pm[m] & 31;
      int sy = y + dy, sx = x + dx;
      val[m] = ((unsigned)sy < 32u) && ((unsigned)sx < 32u);
      srcp[m] = (sy << 5) + sx;
    }
    const u16* wt = wp + (size_t)t * 64 * CH_ * 8;
    for (int k0 = 0; k0 < CH_; k0 += 32) {
      bf8 af[4];
#pragma unroll
      for (int m = 0; m < 4; m++)
        af[m] = val[m] ? *(const bf8*)(inb + (size_t)srcp[m] * CH_ + k0 + lhi * 8) : zero8;
      bf8 bfr[2];
      int cib = (k0 >> 3) + lhi;
#pragma unroll
      for (int n = 0; n < 2; n++) {
        int co = co0 + wc * 32 + n * 16 + l15;
        bfr[n] = *(const bf8*)(wt + ((size_t)cib * CH_ + co) * 8);
      }
#pragma unroll
      for (int m = 0; m < 4; m++)
#pragma unroll
        for (int n = 0; n < 2; n++) acc[m][n] = mfma_bf16(af[m], bfr[n], acc[m][n]);
    }
  }

#pragma unroll
  for (int m = 0; m < 4; m++) {
    int pbase = p0 + wr * 64 + m * 16 + lhi * 4;
#pragma unroll
    for (int n = 0; n < 2; n++) {
      int co = co0 + wc * 32 + n * 16 + l15;
      float bv = bias[co];
#pragma unroll
      for (int r = 0; r < 4; r++) {
        int p = pbase + r;
        size_t idx = ((size_t)b * NSP + p) * CH_ + co;
        float v = acc[m][n][r] + bv;
        if (EPI == 0) outf[idx] = v;
        else if (EPI == 1) outb[idx] = f2bf(v);
        else outf[idx] = v + addf[idx];
      }
    }
  }
}

// ---------------- GroupNorm ----------------
// MODE 0: y = silu(gn(x))              -> outb (bf16 NHWC)
// MODE 1: y = gn(x)*(1+cond)+resid     -> outf (f32) + outb (bf16)
template <int MODE>
__global__ __launch_bounds__(256) void gn_kernel(
    const float* __restrict__ in, const float* __restrict__ gw, const float* __restrict__ gb,
    const float* __restrict__ cond, const float* __restrict__ resid,
    float* __restrict__ outf, u16* __restrict__ outb) {
  int b = blockIdx.y, g = blockIdx.x;
  int tid = threadIdx.x;
  int c = g * 8 + (tid & 7);
  int prow = tid >> 3;            // 0..31
  const float* base = in + (size_t)b * NSP * CH_ + c;
  float v[32];
  float s = 0.f, ss = 0.f;
#pragma unroll
  for (int i = 0; i < 32; i++) {
    v[i] = base[(size_t)(prow + i * 32) * CH_];
    s += v[i]; ss += v[i] * v[i];
  }
  __shared__ float rs[256], rss[256];
  rs[tid] = s; rss[tid] = ss;
  __syncthreads();
  for (int off = 128; off > 0; off >>= 1) {
    if (tid < off) { rs[tid] += rs[tid + off]; rss[tid] += rss[tid + off]; }
    __syncthreads();
  }
  float mean = rs[0] * (1.f / 8192.f);
  float var = rss[0] * (1.f / 8192.f) - mean * mean;
  float inv = rsqrtf(var + 1e-5f);
  float gamma = gw[c], beta = gb[c];
  float cm = 0.f;
  if (MODE == 1) cm = 1.f + cond[b * CH_ + c];
#pragma unroll
  for (int i = 0; i < 32; i++) {
    int p = prow + i * 32;
    size_t idx = ((size_t)b * NSP + p) * CH_ + c;
    float y = (v[i] - mean) * inv * gamma + beta;
    if (MODE == 0) {
      float sg = 1.f / (1.f + __expf(-y));
      outb[idx] = f2bf(y * sg);
    } else {
      float z = y * cm + resid[idx];
      outf[idx] = z;
      outb[idx] = f2bf(z);
    }
  }
}

// ---------------- flash attention ----------------
// q,k,v bf16 NHWC [B][1024][512], c = head*64+d ; out ao bf16 NHWC
__global__ __launch_bounds__(256) void attn_kernel(const u16* __restrict__ q, const u16* __restrict__ k,
                                                   const u16* __restrict__ v, u16* __restrict__ ao) {
  int b = blockIdx.z, hd = blockIdx.y, qt = blockIdx.x;
  int tid = threadIdx.x, lane = tid & 63, wid = tid >> 6;
  int l15 = lane & 15, lhi = lane >> 4;
  int q0 = qt * 64 + wid * 16;
  int cb = hd * HD;
  const u16* qp = q + (size_t)b * NSP * CH_ + cb;
  const u16* kp = k + (size_t)b * NSP * CH_ + cb;
  const u16* vp = v + (size_t)b * NSP * CH_ + cb;

  bf8 aq[2];
#pragma unroll
  for (int ks = 0; ks < 2; ks++)
    aq[ks] = *(const bf8*)(qp + (size_t)(q0 + l15) * CH_ + ks * 32 + lhi * 8);

  f32x4 o[4];
#pragma unroll
  for (int n = 0; n < 4; n++) o[n] = {0.f, 0.f, 0.f, 0.f};
  float mrow[4], lrow[4];
#pragma unroll
  for (int r = 0; r < 4; r++) { mrow[r] = -1e30f; lrow[r] = 0.f; }

  __shared__ u16 Vt[64][64];        // [d][kpos]
  __shared__ u16 P[4][16][64];      // [wave][q_local][kpos]

  for (int kt = 0; kt < 16; ++kt) {
    __syncthreads();                 // prev PV done with Vt
    {
      int kpos = tid >> 2, d0 = (tid & 3) * 16;
      const u16* src = vp + (size_t)(kt * 64 + kpos) * CH_ + d0;
#pragma unroll
      for (int j = 0; j < 16; j++) Vt[d0 + j][kpos] = src[j];
    }
    __syncthreads();                 // Vt ready

    f32x4 s[4];
#pragma unroll
    for (int nf = 0; nf < 4; nf++) {
      f32x4 a = {0.f, 0.f, 0.f, 0.f};
#pragma unroll
      for (int ks = 0; ks < 2; ks++) {
        bf8 bk = *(const bf8*)(kp + (size_t)(kt * 64 + nf * 16 + l15) * CH_ + ks * 32 + lhi * 8);
        a = mfma_bf16(aq[ks], bk, a);
      }
#pragma unroll
      for (int r = 0; r < 4; r++) a[r] *= 0.125f;   // d^-0.5
      s[nf] = a;
    }
    float vm[4];
#pragma unroll
    for (int r = 0; r < 4; r++) {
      float mx = s[0][r];
#pragma unroll
      for (int nf = 1; nf < 4; nf++) mx = fmaxf(mx, s[nf][r]);
      vm[r] = mx;
    }
#pragma unroll
    for (int msk = 1; msk < 16; msk <<= 1)
#pragma unroll
      for (int r = 0; r < 4; r++) vm[r] = fmaxf(vm[r], __shfl_xor(vm[r], msk, 64));
    float corr[4], rsum[4];
#pragma unroll
    for (int r = 0; r < 4; r++) {
      float mn = fmaxf(mrow[r], vm[r]);
      corr[r] = __expf(mrow[r] - mn);
      mrow[r] = mn;
      rsum[r] = 0.f;
    }
#pragma unroll
    for (int nf = 0; nf < 4; nf++)
#pragma unroll
      for (int r = 0; r < 4; r++) {
        float pv = __expf(s[nf][r] - mrow[r]);
        rsum[r] += pv;
        P[wid][lhi * 4 + r][nf * 16 + l15] = f2bf(pv);
      }
#pragma unroll
    for (int msk = 1; msk < 16; msk <<= 1)
#pragma unroll
      for (int r = 0; r < 4; r++) rsum[r] += __shfl_xor(rsum[r], msk, 64);
#pragma unroll
    for (int r = 0; r < 4; r++) lrow[r] = lrow[r] * corr[r] + rsum[r];
#pragma unroll
    for (int n = 0; n < 4; n++)
#pragma unroll
      for (int r = 0; r < 4; r++) o[n][r] *= corr[r];
    // PV
#pragma unroll
    for (int nf = 0; nf < 4; nf++) {
#pragma unroll
      for (int ks = 0; ks < 2; ks++) {
        bf8 ap = *(const bf8*)&P[wid][l15][ks * 32 + lhi * 8];
        bf8 bv = *(const bf8*)&Vt[nf * 16 + l15][ks * 32 + lhi * 8];
        o[nf] = mfma_bf16(ap, bv, o[nf]);
      }
    }
  }
#pragma unroll
  for (int nf = 0; nf < 4; nf++)
#pragma unroll
    for (int r = 0; r < 4; r++) {
      float val = o[nf][r] / lrow[r];
      ao[((size_t)b * NSP + q0 + lhi * 4 + r) * CH_ + cb + nf * 16 + l15] = f2bf(val);
    }
}

// ---------------- launch ----------------

extern "C" void kernel_launch(void* const* d_in, const int* in_sizes, int n_in,
                              void* d_out, int out_size, void* d_ws, size_t ws_size,
                              hipStream_t stream) {
  const float* x    = (const float*)d_in[0];
  const float* cnd  = (const float*)d_in[1];
  const float* c1w  = (const float*)d_in[2];
  const float* c1b  = (const float*)d_in[3];
  const float* g1w  = (const float*)d_in[4];
  const float* g1b  = (const float*)d_in[5];
  const float* c2w  = (const float*)d_in[6];
  const float* c2b  = (const float*)d_in[7];
  const float* g2w  = (const float*)d_in[8];
  const float* g2b  = (const float*)d_in[9];
  const float* cpw  = (const float*)d_in[10];
  const float* cpb  = (const float*)d_in[11];
  const float* rpw  = (const float*)d_in[12];
  const float* rpb  = (const float*)d_in[13];
  const float* qw   = (const float*)d_in[14];
  const float* qb   = (const float*)d_in[15];
  const float* kw   = (const float*)d_in[16];
  const float* kb   = (const float*)d_in[17];
  const float* vw   = (const float*)d_in[18];
  const float* vb   = (const float*)d_in[19];
  const float* ow   = (const float*)d_in[20];
  const float* ob   = (const float*)d_in[21];
  float* out = (float*)d_out;

  char* ws = (char*)d_ws;
  size_t off = 0;
  auto alloc = [&](size_t bytes) -> char* {
    char* p = ws + off;
    off = (off + bytes + 255) & ~(size_t)255;
    return p;
  };
  const size_t ACT_F = (size_t)NB * NSP * CH_ * 4;   // 16 MB
  const size_t ACT_B = (size_t)NB * NSP * CH_ * 2;   // 8 MB

  u16* xb    = (u16*)alloc(ACT_B);               // x NHWC bf16; reused as attn out
  u16* w1p   = (u16*)alloc((size_t)9 * CH_ * CH_ * 2);
  u16* w2p   = (u16*)alloc((size_t)9 * CH_ * CH_ * 2);
  u16* wrp   = (u16*)alloc((size_t)CH_ * CH_ * 2);
  u16* wqp   = (u16*)alloc((size_t)CH_ * CH_ * 2);
  u16* wkp   = (u16*)alloc((size_t)CH_ * CH_ * 2);
  u16* wvp   = (u16*)alloc((size_t)CH_ * CH_ * 2);
  u16* wop   = (u16*)alloc((size_t)CH_ * CH_ * 2);
  float* cndv = (float*)alloc((size_t)NB * CH_ * 4);
  float* resid = (float*)alloc(ACT_F);           // residual; reused as final NHWC
  float* h12  = (float*)alloc(ACT_F);            // conv1 out, then conv2 out
  u16* h1b   = (u16*)alloc(ACT_B);
  float* hbuf = (float*)alloc(ACT_F);            // h (f32 NHWC)
  u16* hb    = (u16*)alloc(ACT_B);
  u16* qbuf  = (u16*)alloc(ACT_B);
  u16* kbuf  = (u16*)alloc(ACT_B);
  u16* vbuf  = (u16*)alloc(ACT_B);
  if (off > ws_size) return;   // workspace too small — fail visibly

  dim3 tgrid(NSP / 32, CH_ / 32, NB);
  pack_x_kernel<<<tgrid, 1024, 0, stream>>>(x, xb);
  pack_w3_kernel<<<(9 * 64 * CH_ + 255) / 256, 256, 0, stream>>>(c1w, w1p);
  pack_w3_kernel<<<(9 * 64 * CH_ + 255) / 256, 256, 0, stream>>>(c2w, w2p);
  pack_w1_kernel<<<(64 * CH_) / 256, 256, 0, stream>>>(rpw, wrp);
  pack_w1_kernel<<<(64 * CH_) / 256, 256, 0, stream>>>(qw, wqp);
  pack_w1_kernel<<<(64 * CH_) / 256, 256, 0, stream>>>(kw, wkp);
  pack_w1_kernel<<<(64 * CH_) / 256, 256, 0, stream>>>(vw, wvp);
  pack_w1_kernel<<<(64 * CH_) / 256, 256, 0, stream>>>(ow, wop);
  cond_kernel<<<dim3(CH_ / 4, NB), 256, 0, stream>>>(cnd, cpw, cpb, cndv);

  dim3 ggrid(NSP / 128, CH_ / 64, NB);
  // conv1 (3x3) -> h12 f32 ; residual proj (1x1) -> resid f32
  conv_gemm_kernel<9, 0><<<ggrid, 256, 0, stream>>>(xb, w1p, c1b, h12, nullptr, nullptr);
  conv_gemm_kernel<1, 0><<<ggrid, 256, 0, stream>>>(xb, wrp, rpb, resid, nullptr, nullptr);
  // gn1 + silu -> h1b bf16
  gn_kernel<0><<<dim3(NGROUP, NB), 256, 0, stream>>>(h12, g1w, g1b, nullptr, nullptr, nullptr, h1b);
  // conv2 (3x3) -> h12 f32
  conv_gemm_kernel<9, 0><<<ggrid, 256, 0, stream>>>(h1b, w2p, c2b, h12, nullptr, nullptr);
  // gn2 * (1+cond) + resid -> hbuf f32, hb bf16
  gn_kernel<1><<<dim3(NGROUP, NB), 256, 0, stream>>>(h12, g2w, g2b, cndv, resid, hbuf, hb);
  // q, k, v (1x1) -> bf16
  conv_gemm_kernel<1, 1><<<ggrid, 256, 0, stream>>>(hb, wqp, qb, nullptr, qbuf, nullptr);
  conv_gemm_kernel<1, 1><<<ggrid, 256, 0, stream>>>(hb, wkp, kb, nullptr, kbuf, nullptr);
  conv_gemm_kernel<1, 1><<<ggrid, 256, 0, stream>>>(hb, wvp, vb, nullptr, vbuf, nullptr);
  // attention -> xb (reused) bf16 NHWC
  attn_kernel<<<dim3(16, HEADS_, NB), 256, 0, stream>>>(qbuf, kbuf, vbuf, xb);
  // out proj + h -> resid (NHWC f32, reused), then transpose to NCHW d_out
  conv_gemm_kernel<1, 2><<<ggrid, 256, 0, stream>>>(xb, wop, ob, resid, nullptr, hbuf);
  transpose_out_kernel<<<tgrid, 1024, 0, stream>>>(resid, out);
}

// Round 2
// 353.048 us; speedup vs baseline: 1.6635x; 1.6635x over previous
//
#include <hip/hip_runtime.h>
#include <hip/hip_bf16.h>

typedef unsigned short u16;
typedef __attribute__((ext_vector_type(8))) short bf8;   // 8 bf16 (raw bits, 4 VGPRs)
typedef __attribute__((ext_vector_type(4))) float f32x4;

#define CH_ 512
#define NSP 1024      // 32*32 spatial
#define NB 8
#define CONDDIM 1280
#define NGROUP 64     // 512/8
#define HEADS_ 8
#define HD 64         // head dim
#define PR 34         // padded row length (32 + 2)
#define PPB (PR*PR)   // padded positions per batch = 1156

__device__ __forceinline__ u16 f2bf(float f) {
  union { float f; unsigned u; } v; v.f = f;
  unsigned u = v.u;
  return (u16)((u + 0x7fffu + ((u >> 16) & 1u)) >> 16);   // RNE
}

__device__ __forceinline__ f32x4 mfma_bf16(bf8 a, bf8 b, f32x4 c) {
  return __builtin_amdgcn_mfma_f32_16x16x32_bf16(a, b, c, 0, 0, 0);
}

__device__ __forceinline__ void gload16(const void* g, void* l) {
  __builtin_amdgcn_global_load_lds((const __attribute__((address_space(1))) void*)g,
                                   (__attribute__((address_space(3))) void*)l, 16, 0, 0);
}

// ---------------- pack / transpose kernels ----------------

// x: NCHW f32 -> xp: padded NHWC bf16 [B][34][34][512] (interior only)
__global__ __launch_bounds__(1024) void pack_x_kernel(const float* __restrict__ x, u16* __restrict__ xp) {
  __shared__ float t[32][33];
  int b = blockIdx.z;
  int c0 = blockIdx.y * 32, p0 = blockIdx.x * 32;
  int tx = threadIdx.x & 31, ty = threadIdx.x >> 5;
  t[ty][tx] = x[((size_t)b * CH_ + c0 + ty) * NSP + p0 + tx];
  __syncthreads();
  int p = p0 + ty;
  int y = p >> 5, xc = p & 31;
  xp[((size_t)b * PPB + (size_t)(y + 1) * PR + xc + 1) * CH_ + c0 + tx] = f2bf(t[tx][ty]);
}

// zero the borders of two padded bf16 buffers
__global__ __launch_bounds__(256) void border_zero_kernel(u16* __restrict__ a, u16* __restrict__ b) {
  int id = blockIdx.x * 256 + threadIdx.x;   // (b, border-pos, ch-chunk of 8)
  if (id >= NB * 132 * 64) return;
  int ch8 = id & 63;
  int rest = id >> 6;
  int bidx = rest % 132;
  int bb = rest / 132;
  int r, c;
  if (bidx < 34)       { r = 0;          c = bidx; }
  else if (bidx < 68)  { r = 33;         c = bidx - 34; }
  else if (bidx < 100) { r = bidx - 67;  c = 0; }
  else                 { r = bidx - 99;  c = 33; }
  size_t off = ((size_t)bb * PPB + (size_t)r * PR + c) * CH_ + ch8 * 8;
  const bf8 z = {0, 0, 0, 0, 0, 0, 0, 0};
  *(bf8*)(a + off) = z;
  *(bf8*)(b + off) = z;
}

// NHWC f32 -> NCHW f32 (final output)
__global__ __launch_bounds__(1024) void transpose_out_kernel(const float* __restrict__ in, float* __restrict__ out) {
  __shared__ float t[32][33];
  int b = blockIdx.z;
  int c0 = blockIdx.y * 32, p0 = blockIdx.x * 32;
  int tx = threadIdx.x & 31, ty = threadIdx.x >> 5;
  t[ty][tx] = in[((size_t)b * NSP + p0 + ty) * CH_ + c0 + tx];
  __syncthreads();
  out[((size_t)b * CH_ + c0 + ty) * NSP + p0 + tx] = t[tx][ty];
}

// 3x3 weights [co][ci][3][3] f32 -> packed [t][ci/8][co][8] bf16
__global__ __launch_bounds__(256) void pack_w3_kernel(const float* __restrict__ w, u16* __restrict__ wp) {
  int id = blockIdx.x * 256 + threadIdx.x;        // (t, cib, co)
  if (id >= 9 * 64 * CH_) return;
  int co = id & (CH_ - 1);
  int cib = (id >> 9) & 63;
  int t = id >> 15;
  int dy = t / 3, dx = t % 3;
  bf8 v;
#pragma unroll
  for (int j = 0; j < 8; j++) {
    int ci = cib * 8 + j;
    v[j] = (short)f2bf(w[(((size_t)co * CH_ + ci) * 3 + dy) * 3 + dx]);
  }
  *(bf8*)(wp + ((size_t)(t * 64 + cib) * CH_ + co) * 8) = v;
}

// 1x1 weights [co][ci] f32 -> packed [ci/8][co][8] bf16
__global__ __launch_bounds__(256) void pack_w1_kernel(const float* __restrict__ w, u16* __restrict__ wp) {
  int id = blockIdx.x * 256 + threadIdx.x;        // (cib, co)
  if (id >= 64 * CH_) return;
  int co = id & (CH_ - 1);
  int cib = id >> 9;
  bf8 v;
#pragma unroll
  for (int j = 0; j < 8; j++) v[j] = (short)f2bf(w[(size_t)co * CH_ + cib * 8 + j]);
  *(bf8*)(wp + ((size_t)cib * CH_ + co) * 8) = v;
}

// cond[b][c] = conditioning[b] . cpw[c] + cpb[c]   (f32)
__global__ __launch_bounds__(256) void cond_kernel(const float* __restrict__ cd, const float* __restrict__ cpw,
                                                   const float* __restrict__ cpb, float* __restrict__ cond) {
  int b = blockIdx.y;
  int c = blockIdx.x * 4 + (threadIdx.x >> 6);
  int lane = threadIdx.x & 63;
  const float* wrow = cpw + (size_t)c * CONDDIM;
  const float* crow = cd + (size_t)b * CONDDIM;
  float s = 0.f;
  for (int i = lane; i < CONDDIM; i += 64) s += crow[i] * wrow[i];
#pragma unroll
  for (int m = 32; m > 0; m >>= 1) s += __shfl_xor(s, m, 64);
  if (lane == 0) cond[b * CH_ + c] = s + cpb[c];
}

// ---------------- LDS-staged implicit-GEMM conv ----------------
// TAPS=9: input padded [B][34][34][512]; TAPS=1: PIN picks padded/linear input.
// Tile: 128 pos (4 rows) x 64 co; 4 waves (2 pos-halves x 2 co-halves).
// A LDS: [rows][64ch] with chunk-XOR swizzle (chunk ^= row&7) for conflict-free ds_read_b128.
// B LDS: [8 cib][64 co][8ch], linear.
// 2-phase pipeline: stage(p+1) overlaps compute(p); __syncthreads drains per phase.
// EPI: 0 = f32 out (+bias); 1 = bf16 out (+bias); 2 = f32 out (+bias+addf)
template <int TAPS, int PIN, int EPI>
__global__ __launch_bounds__(256) void conv_kernel(
    const u16* __restrict__ in, const u16* __restrict__ wp, const float* __restrict__ bias,
    float* __restrict__ outf, u16* __restrict__ outb, const float* __restrict__ addf) {
  constexpr int AROWS = (TAPS == 9) ? 208 : 128;   // 204 used (6x34) for 3x3
  constexpr int NPH = TAPS * 8;
  __shared__ u16 Ash[2][AROWS * 64];
  __shared__ u16 Bsh[2][8 * 64 * 8];

  const int b = blockIdx.z;
  const int co0 = blockIdx.y * 64;
  const int p0 = blockIdx.x * 128;
  const int R0 = blockIdx.x * 4;          // output row base
  const int tid = threadIdx.x;
  const int lane = tid & 63, wid = tid >> 6;
  const int wr = wid >> 1, wc = wid & 1;
  const int l15 = lane & 15, lhi = lane >> 4;

  const char* inb = (const char*)in +
      ((TAPS == 9 || PIN) ? ((size_t)b * PPB) * 1024 : ((size_t)b * NSP) * 1024);
  const char* wpb = (const char*)wp;

  auto stageA = [&](int k0, int abuf) {
    char* dst = (char*)Ash[abuf];
    if (TAPS == 9) {
      const char* abase = inb + ((size_t)R0 * PR) * 1024 + k0 * 2;
      for (int i = wid; i < 26; i += 4) {              // 26 KB: rows R0..R0+5, cols 0..33
        int chunk = i * 64 + lane;
        int a = chunk >> 3, cp = chunk & 7;
        int c = cp ^ (a & 7);                           // inverse-swizzle the SOURCE
        gload16(abase + (size_t)a * 1024 + c * 16, dst + i * 1024);
      }
    } else {
      const char* abase = inb + k0 * 2;
      for (int i = wid; i < 16; i += 4) {              // 16 KB: 128 positions
        int chunk = i * 64 + lane;
        int a = chunk >> 3, cp = chunk & 7;
        int c = cp ^ (a & 7);
        int plin = p0 + a;
        int gpos = PIN ? ((plin >> 5) * PR + (plin & 31) + PR + 1) : plin;
        gload16(abase + (size_t)gpos * 1024 + c * 16, dst + i * 1024);
      }
    }
  };
  auto stageB = [&](int t, int k0, int bbuf) {
    const char* wbase = wpb + ((size_t)(t * 64 + (k0 >> 3)) * 512 + co0) * 16;
    char* dst = (char*)Bsh[bbuf];
#pragma unroll
    for (int jj = 0; jj < 2; jj++) {
      int j = wid * 2 + jj;
      gload16(wbase + (size_t)j * 8192 + (size_t)lane * 16, dst + j * 1024);
    }
  };

  f32x4 acc[4][2];
#pragma unroll
  for (int m = 0; m < 4; m++)
#pragma unroll
    for (int n = 0; n < 2; n++) acc[m][n] = {0.f, 0.f, 0.f, 0.f};

  stageB(0, 0, 0);
  stageA(0, 0);

  int t = 0, k0 = 0, ab = 0;
  for (int p = 0; p < NPH; ++p) {
    __syncthreads();                       // stage(p) drained (vmcnt0), readers of p-1 done
    int tn = t + 1, kn = k0, an = ab;
    bool stA = false;
    if (tn == TAPS) { tn = 0; kn += 64; an ^= 1; stA = true; }
    if (p + 1 < NPH) {
      stageB(tn, kn, (p + 1) & 1);
      if (stA) stageA(kn, an);
    }
    // compute phase p: tap t from Ash[ab], Bsh[p&1]
    const int dy = (TAPS == 9) ? (t / 3 - 1) : 0;
    const int dx = (TAPS == 9) ? (t % 3 - 1) : 0;
    bf8 af[4][2];
#pragma unroll
    for (int m = 0; m < 4; m++) {
      int row = wr * 2 + (m >> 1);
      int a0 = (TAPS == 9) ? ((row + dy + 1) * PR + (m & 1) * 16 + dx + 1)
                           : (wr * 64 + m * 16);
      int a = a0 + l15;
      const char* Ab = (const char*)Ash[ab] + (size_t)a * 128;
      int sw = a & 7;
#pragma unroll
      for (int ks = 0; ks < 2; ks++)
        af[m][ks] = *(const bf8*)(Ab + (((ks * 4 + lhi) ^ sw) * 16));
    }
    const char* Bb = (const char*)Bsh[p & 1];
    bf8 bfr[2][2];
#pragma unroll
    for (int n = 0; n < 2; n++)
#pragma unroll
      for (int ks = 0; ks < 2; ks++)
        bfr[n][ks] = *(const bf8*)(Bb + (size_t)(ks * 4 + lhi) * 1024 + (size_t)(wc * 32 + n * 16 + l15) * 16);
#pragma unroll
    for (int ks = 0; ks < 2; ks++)
#pragma unroll
      for (int m = 0; m < 4; m++)
#pragma unroll
        for (int n = 0; n < 2; n++)
          acc[m][n] = mfma_bf16(af[m][ks], bfr[n][ks], acc[m][n]);
    t = tn; k0 = kn; ab = an;
  }

#pragma unroll
  for (int m = 0; m < 4; m++) {
    int pbase = p0 + wr * 64 + m * 16 + lhi * 4;
#pragma unroll
    for (int n = 0; n < 2; n++) {
      int co = co0 + wc * 32 + n * 16 + l15;
      float bv = bias[co];
#pragma unroll
      for (int r = 0; r < 4; r++) {
        int p = pbase + r;
        size_t idx = ((size_t)b * NSP + p) * CH_ + co;
        float v = acc[m][n][r] + bv;
        if (EPI == 0) outf[idx] = v;
        else if (EPI == 1) outb[idx] = f2bf(v);
        else outf[idx] = v + addf[idx];
      }
    }
  }
}

// ---------------- GroupNorm ----------------
// MODE 0: y = silu(gn(x))              -> outb (bf16, PADDED NHWC)
// MODE 1: y = gn(x)*(1+cond)+resid     -> outf (f32, may alias in) + outb (bf16 NHWC)
template <int MODE>
__global__ __launch_bounds__(256) void gn_kernel(
    const float* __restrict__ in, const float* __restrict__ gw, const float* __restrict__ gb,
    const float* __restrict__ cond, const float* __restrict__ resid,
    float* __restrict__ outf, u16* __restrict__ outb) {
  int b = blockIdx.y, g = blockIdx.x;
  int tid = threadIdx.x;
  int c = g * 8 + (tid & 7);
  int prow = tid >> 3;            // 0..31
  const float* base = in + (size_t)b * NSP * CH_ + c;
  float v[32];
  float s = 0.f, ss = 0.f;
#pragma unroll
  for (int i = 0; i < 32; i++) {
    v[i] = base[(size_t)(prow + i * 32) * CH_];
    s += v[i]; ss += v[i] * v[i];
  }
  __shared__ float rs[256], rss[256];
  rs[tid] = s; rss[tid] = ss;
  __syncthreads();
  for (int off = 128; off > 0; off >>= 1) {
    if (tid < off) { rs[tid] += rs[tid + off]; rss[tid] += rss[tid + off]; }
    __syncthreads();
  }
  float mean = rs[0] * (1.f / 8192.f);
  float var = rss[0] * (1.f / 8192.f) - mean * mean;
  float inv = rsqrtf(var + 1e-5f);
  float gamma = gw[c], beta = gb[c];
  float cm = 0.f;
  if (MODE == 1) cm = 1.f + cond[b * CH_ + c];
#pragma unroll
  for (int i = 0; i < 32; i++) {
    int p = prow + i * 32;
    float y = (v[i] - mean) * inv * gamma + beta;
    if (MODE == 0) {
      float sg = 1.f / (1.f + __expf(-y));
      int yy = p >> 5, xc = p & 31;
      outb[((size_t)b * PPB + (size_t)(yy + 1) * PR + xc + 1) * CH_ + c] = f2bf(y * sg);
    } else {
      size_t idx = ((size_t)b * NSP + p) * CH_ + c;
      float z = y * cm + resid[idx];
      outf[idx] = z;
      outb[idx] = f2bf(z);
    }
  }
}

// ---------------- flash attention ----------------
__global__ __launch_bounds__(256) void attn_kernel(const u16* __restrict__ q, const u16* __restrict__ k,
                                                   const u16* __restrict__ v, u16* __restrict__ ao) {
  int b = blockIdx.z, hd = blockIdx.y, qt = blockIdx.x;
  int tid = threadIdx.x, lane = tid & 63, wid = tid >> 6;
  int l15 = lane & 15, lhi = lane >> 4;
  int q0 = qt * 64 + wid * 16;
  int cb = hd * HD;
  const u16* qp = q + (size_t)b * NSP * CH_ + cb;
  const u16* kp = k + (size_t)b * NSP * CH_ + cb;
  const u16* vp = v + (size_t)b * NSP * CH_ + cb;

  bf8 aq[2];
#pragma unroll
  for (int ks = 0; ks < 2; ks++)
    aq[ks] = *(const bf8*)(qp + (size_t)(q0 + l15) * CH_ + ks * 32 + lhi * 8);

  f32x4 o[4];
#pragma unroll
  for (int n = 0; n < 4; n++) o[n] = {0.f, 0.f, 0.f, 0.f};
  float mrow[4], lrow[4];
#pragma unroll
  for (int r = 0; r < 4; r++) { mrow[r] = -1e30f; lrow[r] = 0.f; }

  __shared__ u16 Vt[64][64];        // [d][kpos]
  __shared__ u16 P[4][16][64];      // [wave][q_local][kpos]

  for (int kt = 0; kt < 16; ++kt) {
    __syncthreads();
    {
      int kpos = tid >> 2, d0 = (tid & 3) * 16;
      const u16* src = vp + (size_t)(kt * 64 + kpos) * CH_ + d0;
#pragma unroll
      for (int j = 0; j < 16; j++) Vt[d0 + j][kpos] = src[j];
    }
    __syncthreads();

    f32x4 s[4];
#pragma unroll
    for (int nf = 0; nf < 4; nf++) {
      f32x4 a = {0.f, 0.f, 0.f, 0.f};
#pragma unroll
      for (int ks = 0; ks < 2; ks++) {
        bf8 bk = *(const bf8*)(kp + (size_t)(kt * 64 + nf * 16 + l15) * CH_ + ks * 32 + lhi * 8);
        a = mfma_bf16(aq[ks], bk, a);
      }
#pragma unroll
      for (int r = 0; r < 4; r++) a[r] *= 0.125f;
      s[nf] = a;
    }
    float vm[4];
#pragma unroll
    for (int r = 0; r < 4; r++) {
      float mx = s[0][r];
#pragma unroll
      for (int nf = 1; nf < 4; nf++) mx = fmaxf(mx, s[nf][r]);
      vm[r] = mx;
    }
#pragma unroll
    for (int msk = 1; msk < 16; msk <<= 1)
#pragma unroll
      for (int r = 0; r < 4; r++) vm[r] = fmaxf(vm[r], __shfl_xor(vm[r], msk, 64));
    float corr[4], rsum[4];
#pragma unroll
    for (int r = 0; r < 4; r++) {
      float mn = fmaxf(mrow[r], vm[r]);
      corr[r] = __expf(mrow[r] - mn);
      mrow[r] = mn;
      rsum[r] = 0.f;
    }
#pragma unroll
    for (int nf = 0; nf < 4; nf++)
#pragma unroll
      for (int r = 0; r < 4; r++) {
        float pv = __expf(s[nf][r] - mrow[r]);
        rsum[r] += pv;
        P[wid][lhi * 4 + r][nf * 16 + l15] = f2bf(pv);
      }
#pragma unroll
    for (int msk = 1; msk < 16; msk <<= 1)
#pragma unroll
      for (int r = 0; r < 4; r++) rsum[r] += __shfl_xor(rsum[r], msk, 64);
#pragma unroll
    for (int r = 0; r < 4; r++) lrow[r] = lrow[r] * corr[r] + rsum[r];
#pragma unroll
    for (int n = 0; n < 4; n++)
#pragma unroll
      for (int r = 0; r < 4; r++) o[n][r] *= corr[r];
#pragma unroll
    for (int nf = 0; nf < 4; nf++) {
#pragma unroll
      for (int ks = 0; ks < 2; ks++) {
        bf8 ap = *(const bf8*)&P[wid][l15][ks * 32 + lhi * 8];
        bf8 bv = *(const bf8*)&Vt[nf * 16 + l15][ks * 32 + lhi * 8];
        o[nf] = mfma_bf16(ap, bv, o[nf]);
      }
    }
  }
#pragma unroll
  for (int nf = 0; nf < 4; nf++)
#pragma unroll
    for (int r = 0; r < 4; r++) {
      float val = o[nf][r] / lrow[r];
      ao[((size_t)b * NSP + q0 + lhi * 4 + r) * CH_ + cb + nf * 16 + l15] = f2bf(val);
    }
}

// ---------------- launch ----------------

extern "C" void kernel_launch(void* const* d_in, const int* in_sizes, int n_in,
                              void* d_out, int out_size, void* d_ws, size_t ws_size,
                              hipStream_t stream) {
  const float* x    = (const float*)d_in[0];
  const float* cnd  = (const float*)d_in[1];
  const float* c1w  = (const float*)d_in[2];
  const float* c1b  = (const float*)d_in[3];
  const float* g1w  = (const float*)d_in[4];
  const float* g1b  = (const float*)d_in[5];
  const float* c2w  = (const float*)d_in[6];
  const float* c2b  = (const float*)d_in[7];
  const float* g2w  = (const float*)d_in[8];
  const float* g2b  = (const float*)d_in[9];
  const float* cpw  = (const float*)d_in[10];
  const float* cpb  = (const float*)d_in[11];
  const float* rpw  = (const float*)d_in[12];
  const float* rpb  = (const float*)d_in[13];
  const float* qw   = (const float*)d_in[14];
  const float* qb   = (const float*)d_in[15];
  const float* kw   = (const float*)d_in[16];
  const float* kb   = (const float*)d_in[17];
  const float* vw   = (const float*)d_in[18];
  const float* vb   = (const float*)d_in[19];
  const float* ow   = (const float*)d_in[20];
  const float* ob   = (const float*)d_in[21];
  float* out = (float*)d_out;

  char* ws = (char*)d_ws;
  size_t off = 0;
  auto alloc = [&](size_t bytes) -> char* {
    char* p = ws + off;
    off = (off + bytes + 255) & ~(size_t)255;
    return p;
  };
  const size_t ACT_F = (size_t)NB * NSP * CH_ * 4;   // 16 MB
  const size_t ACT_B = (size_t)NB * NSP * CH_ * 2;   // 8 MB
  const size_t PAD_B = (size_t)NB * PPB * CH_ * 2;   // 9.47 MB

  u16* xp    = (u16*)alloc(PAD_B);               // x padded NHWC bf16
  u16* h1p   = (u16*)alloc(PAD_B);               // silu(gn1) padded bf16
  u16* w1p   = (u16*)alloc((size_t)9 * CH_ * CH_ * 2);
  u16* w2p   = (u16*)alloc((size_t)9 * CH_ * CH_ * 2);
  u16* wrp   = (u16*)alloc((size_t)CH_ * CH_ * 2);
  u16* wqp   = (u16*)alloc((size_t)CH_ * CH_ * 2);
  u16* wkp   = (u16*)alloc((size_t)CH_ * CH_ * 2);
  u16* wvp   = (u16*)alloc((size_t)CH_ * CH_ * 2);
  u16* wop   = (u16*)alloc((size_t)CH_ * CH_ * 2);
  float* cndv = (float*)alloc((size_t)NB * CH_ * 4);
  float* resid = (float*)alloc(ACT_F);           // residual; reused as final NHWC f32
  float* h12  = (float*)alloc(ACT_F);            // conv outs; gn2 in-place -> h (f32)
  u16* hb    = (u16*)alloc(ACT_B);               // h bf16 (attn input)
  u16* qbuf  = (u16*)alloc(ACT_B);
  u16* kbuf  = (u16*)alloc(ACT_B);
  u16* vbuf  = (u16*)alloc(ACT_B);
  u16* aob   = (u16*)alloc(ACT_B);               // attention out bf16
  if (off > ws_size) return;

  dim3 tgrid(NSP / 32, CH_ / 32, NB);
  border_zero_kernel<<<(NB * 132 * 64 + 255) / 256, 256, 0, stream>>>(xp, h1p);
  pack_x_kernel<<<tgrid, 1024, 0, stream>>>(x, xp);
  pack_w3_kernel<<<(9 * 64 * CH_ + 255) / 256, 256, 0, stream>>>(c1w, w1p);
  pack_w3_kernel<<<(9 * 64 * CH_ + 255) / 256, 256, 0, stream>>>(c2w, w2p);
  pack_w1_kernel<<<(64 * CH_) / 256, 256, 0, stream>>>(rpw, wrp);
  pack_w1_kernel<<<(64 * CH_) / 256, 256, 0, stream>>>(qw, wqp);
  pack_w1_kernel<<<(64 * CH_) / 256, 256, 0, stream>>>(kw, wkp);
  pack_w1_kernel<<<(64 * CH_) / 256, 256, 0, stream>>>(vw, wvp);
  pack_w1_kernel<<<(64 * CH_) / 256, 256, 0, stream>>>(ow, wop);
  cond_kernel<<<dim3(CH_ / 4, NB), 256, 0, stream>>>(cnd, cpw, cpb, cndv);

  dim3 ggrid(NSP / 128, CH_ / 64, NB);
  // conv1 (3x3, padded in) -> h12 f32 ; residual proj (1x1, padded in) -> resid f32
  conv_kernel<9, 1, 0><<<ggrid, 256, 0, stream>>>(xp, w1p, c1b, h12, nullptr, nullptr);
  conv_kernel<1, 1, 0><<<ggrid, 256, 0, stream>>>(xp, wrp, rpb, resid, nullptr, nullptr);
  // gn1 + silu -> h1p (padded bf16)
  gn_kernel<0><<<dim3(NGROUP, NB), 256, 0, stream>>>(h12, g1w, g1b, nullptr, nullptr, nullptr, h1p);
  // conv2 (3x3, padded in) -> h12 f32
  conv_kernel<9, 1, 0><<<ggrid, 256, 0, stream>>>(h1p, w2p, c2b, h12, nullptr, nullptr);
  // gn2 * (1+cond) + resid -> h12 (in-place f32), hb bf16
  gn_kernel<1><<<dim3(NGROUP, NB), 256, 0, stream>>>(h12, g2w, g2b, cndv, resid, h12, hb);
  // q, k, v (1x1) -> bf16
  conv_kernel<1, 0, 1><<<ggrid, 256, 0, stream>>>(hb, wqp, qb, nullptr, qbuf, nullptr);
  conv_kernel<1, 0, 1><<<ggrid, 256, 0, stream>>>(hb, wkp, kb, nullptr, kbuf, nullptr);
  conv_kernel<1, 0, 1><<<ggrid, 256, 0, stream>>>(hb, wvp, vb, nullptr, vbuf, nullptr);
  // attention -> aob bf16
  attn_kernel<<<dim3(16, HEADS_, NB), 256, 0, stream>>>(qbuf, kbuf, vbuf, aob);
  // out proj + h -> resid (NHWC f32), then transpose to NCHW d_out
  conv_kernel<1, 0, 2><<<ggrid, 256, 0, stream>>>(aob, wop, ob, resid, nullptr, h12);
  transpose_out_kernel<<<tgrid, 1024, 0, stream>>>(resid, out);
}

// Round 3
// 304.252 us; speedup vs baseline: 1.9302x; 1.1604x over previous
//
#include <hip/hip_runtime.h>
#include <hip/hip_bf16.h>

typedef unsigned short u16;
typedef __attribute__((ext_vector_type(8))) short bf8;   // 8 bf16 (raw bits, 4 VGPRs)
typedef __attribute__((ext_vector_type(4))) short bf4;   // 4 bf16 (2 VGPRs)
typedef __attribute__((ext_vector_type(4))) float f32x4;

#define CH_ 512
#define NSP 1024      // 32*32 spatial
#define NB 8
#define CONDDIM 1280
#define NGROUP 64     // 512/8
#define HEADS_ 8
#define HD 64         // head dim
#define PR 34         // padded row length (32 + 2)
#define PPB (PR*PR)   // padded positions per batch = 1156

__device__ __forceinline__ u16 f2bf(float f) {
  union { float f; unsigned u; } v; v.f = f;
  unsigned u = v.u;
  return (u16)((u + 0x7fffu + ((u >> 16) & 1u)) >> 16);   // RNE
}

__device__ __forceinline__ unsigned cvt_pk_bf16(float lo, float hi) {
  unsigned r;
  asm volatile("v_cvt_pk_bf16_f32 %0, %1, %2" : "=v"(r) : "v"(lo), "v"(hi));
  return r;
}

__device__ __forceinline__ f32x4 mfma_bf16(bf8 a, bf8 b, f32x4 c) {
  return __builtin_amdgcn_mfma_f32_16x16x32_bf16(a, b, c, 0, 0, 0);
}

__device__ __forceinline__ void gload16(const void* g, void* l) {
  __builtin_amdgcn_global_load_lds((const __attribute__((address_space(1))) void*)g,
                                   (__attribute__((address_space(3))) void*)l, 16, 0, 0);
}

// ---------------- pack / transpose kernels ----------------

// x: NCHW f32 -> xp: padded NHWC bf16 [B][34][34][512] (interior only)
__global__ __launch_bounds__(1024) void pack_x_kernel(const float* __restrict__ x, u16* __restrict__ xp) {
  __shared__ float t[32][33];
  int b = blockIdx.z;
  int c0 = blockIdx.y * 32, p0 = blockIdx.x * 32;
  int tx = threadIdx.x & 31, ty = threadIdx.x >> 5;
  t[ty][tx] = x[((size_t)b * CH_ + c0 + ty) * NSP + p0 + tx];
  __syncthreads();
  int p = p0 + ty;
  int y = p >> 5, xc = p & 31;
  xp[((size_t)b * PPB + (size_t)(y + 1) * PR + xc + 1) * CH_ + c0 + tx] = f2bf(t[tx][ty]);
}

// zero the borders of two padded bf16 buffers
__global__ __launch_bounds__(256) void border_zero_kernel(u16* __restrict__ a, u16* __restrict__ b) {
  int id = blockIdx.x * 256 + threadIdx.x;   // (b, border-pos, ch-chunk of 8)
  if (id >= NB * 132 * 64) return;
  int ch8 = id & 63;
  int rest = id >> 6;
  int bidx = rest % 132;
  int bb = rest / 132;
  int r, c;
  if (bidx < 34)       { r = 0;          c = bidx; }
  else if (bidx < 68)  { r = 33;         c = bidx - 34; }
  else if (bidx < 100) { r = bidx - 67;  c = 0; }
  else                 { r = bidx - 99;  c = 33; }
  size_t off = ((size_t)bb * PPB + (size_t)r * PR + c) * CH_ + ch8 * 8;
  const bf8 z = {0, 0, 0, 0, 0, 0, 0, 0};
  *(bf8*)(a + off) = z;
  *(bf8*)(b + off) = z;
}

// NHWC f32 -> NCHW f32 (final output)
__global__ __launch_bounds__(1024) void transpose_out_kernel(const float* __restrict__ in, float* __restrict__ out) {
  __shared__ float t[32][33];
  int b = blockIdx.z;
  int c0 = blockIdx.y * 32, p0 = blockIdx.x * 32;
  int tx = threadIdx.x & 31, ty = threadIdx.x >> 5;
  t[ty][tx] = in[((size_t)b * NSP + p0 + ty) * CH_ + c0 + tx];
  __syncthreads();
  out[((size_t)b * CH_ + c0 + ty) * NSP + p0 + tx] = t[tx][ty];
}

// 3x3 weights [co][ci][3][3] f32 -> packed [t][ci/8][co][8] bf16
__global__ __launch_bounds__(256) void pack_w3_kernel(const float* __restrict__ w, u16* __restrict__ wp) {
  int id = blockIdx.x * 256 + threadIdx.x;        // (t, cib, co)
  if (id >= 9 * 64 * CH_) return;
  int co = id & (CH_ - 1);
  int cib = (id >> 9) & 63;
  int t = id >> 15;
  int dy = t / 3, dx = t % 3;
  bf8 v;
#pragma unroll
  for (int j = 0; j < 8; j++) {
    int ci = cib * 8 + j;
    v[j] = (short)f2bf(w[(((size_t)co * CH_ + ci) * 3 + dy) * 3 + dx]);
  }
  *(bf8*)(wp + ((size_t)(t * 64 + cib) * CH_ + co) * 8) = v;
}

// 1x1 weights [co][ci] f32 -> packed [ci/8][co][8] bf16
__global__ __launch_bounds__(256) void pack_w1_kernel(const float* __restrict__ w, u16* __restrict__ wp) {
  int id = blockIdx.x * 256 + threadIdx.x;        // (cib, co)
  if (id >= 64 * CH_) return;
  int co = id & (CH_ - 1);
  int cib = id >> 9;
  bf8 v;
#pragma unroll
  for (int j = 0; j < 8; j++) v[j] = (short)f2bf(w[(size_t)co * CH_ + cib * 8 + j]);
  *(bf8*)(wp + ((size_t)cib * CH_ + co) * 8) = v;
}

// cond[b][c] = conditioning[b] . cpw[c] + cpb[c]   (f32)
__global__ __launch_bounds__(256) void cond_kernel(const float* __restrict__ cd, const float* __restrict__ cpw,
                                                   const float* __restrict__ cpb, float* __restrict__ cond) {
  int b = blockIdx.y;
  int c = blockIdx.x * 4 + (threadIdx.x >> 6);
  int lane = threadIdx.x & 63;
  const float* wrow = cpw + (size_t)c * CONDDIM;
  const float* crow = cd + (size_t)b * CONDDIM;
  float s = 0.f;
  for (int i = lane; i < CONDDIM; i += 64) s += crow[i] * wrow[i];
#pragma unroll
  for (int m = 32; m > 0; m >>= 1) s += __shfl_xor(s, m, 64);
  if (lane == 0) cond[b * CH_ + c] = s + cpb[c];
}

// ---------------- LDS-staged implicit-GEMM conv ----------------
// TAPS=9: input padded [B][34][34][512]; TAPS=1: PIN picks padded/linear input.
// Tile: 128 pos (4 rows) x 64 co; 4 waves (2 pos-halves x 2 co-halves).
// A LDS: [rows][64ch] with chunk-XOR swizzle (chunk ^= row&7) for conflict-free ds_read_b128.
// B LDS: [8 cib][64 co][8ch], linear.
// EPI: 0 = f32 out (+bias); 1 = bf16 out (+bias); 2 = f32 out (+bias+addf);
//      3 = bf16 out scaled by 0.125 (Q);  4 = bf16 transposed [B][C][N] out (V^T)
template <int TAPS, int PIN, int EPI>
__global__ __launch_bounds__(256) void conv_kernel(
    const u16* __restrict__ in, const u16* __restrict__ wp, const float* __restrict__ bias,
    float* __restrict__ outf, u16* __restrict__ outb, const float* __restrict__ addf) {
  constexpr int AROWS = (TAPS == 9) ? 208 : 128;   // 204 used (6x34) for 3x3
  constexpr int NPH = TAPS * 8;
  __shared__ u16 Ash[2][AROWS * 64];
  __shared__ u16 Bsh[2][8 * 64 * 8];

  const int b = blockIdx.z;
  const int co0 = blockIdx.y * 64;
  const int p0 = blockIdx.x * 128;
  const int R0 = blockIdx.x * 4;          // output row base
  const int tid = threadIdx.x;
  const int lane = tid & 63, wid = tid >> 6;
  const int wr = wid >> 1, wc = wid & 1;
  const int l15 = lane & 15, lhi = lane >> 4;

  const char* inb = (const char*)in +
      ((TAPS == 9 || PIN) ? ((size_t)b * PPB) * 1024 : ((size_t)b * NSP) * 1024);
  const char* wpb = (const char*)wp;

  auto stageA = [&](int k0, int abuf) {
    char* dst = (char*)Ash[abuf];
    if (TAPS == 9) {
      const char* abase = inb + ((size_t)R0 * PR) * 1024 + k0 * 2;
      for (int i = wid; i < 26; i += 4) {              // 26 KB: rows R0..R0+5, cols 0..33
        int chunk = i * 64 + lane;
        int a = chunk >> 3, cp = chunk & 7;
        int c = cp ^ (a & 7);                           // inverse-swizzle the SOURCE
        gload16(abase + (size_t)a * 1024 + c * 16, dst + i * 1024);
      }
    } else {
      const char* abase = inb + k0 * 2;
      for (int i = wid; i < 16; i += 4) {              // 16 KB: 128 positions
        int chunk = i * 64 + lane;
        int a = chunk >> 3, cp = chunk & 7;
        int c = cp ^ (a & 7);
        int plin = p0 + a;
        int gpos = PIN ? ((plin >> 5) * PR + (plin & 31) + PR + 1) : plin;
        gload16(abase + (size_t)gpos * 1024 + c * 16, dst + i * 1024);
      }
    }
  };
  auto stageB = [&](int t, int k0, int bbuf) {
    const char* wbase = wpb + ((size_t)(t * 64 + (k0 >> 3)) * 512 + co0) * 16;
    char* dst = (char*)Bsh[bbuf];
#pragma unroll
    for (int jj = 0; jj < 2; jj++) {
      int j = wid * 2 + jj;
      gload16(wbase + (size_t)j * 8192 + (size_t)lane * 16, dst + j * 1024);
    }
  };

  f32x4 acc[4][2];
#pragma unroll
  for (int m = 0; m < 4; m++)
#pragma unroll
    for (int n = 0; n < 2; n++) acc[m][n] = {0.f, 0.f, 0.f, 0.f};

  stageB(0, 0, 0);
  stageA(0, 0);

  int t = 0, k0 = 0, ab = 0;
  for (int p = 0; p < NPH; ++p) {
    __syncthreads();                       // stage(p) drained (vmcnt0), readers of p-1 done
    int tn = t + 1, kn = k0, an = ab;
    bool stA = false;
    if (tn == TAPS) { tn = 0; kn += 64; an ^= 1; stA = true; }
    if (p + 1 < NPH) {
      stageB(tn, kn, (p + 1) & 1);
      if (stA) stageA(kn, an);
    }
    // compute phase p: tap t from Ash[ab], Bsh[p&1]
    const int dy = (TAPS == 9) ? (t / 3 - 1) : 0;
    const int dx = (TAPS == 9) ? (t % 3 - 1) : 0;
    bf8 af[4][2];
#pragma unroll
    for (int m = 0; m < 4; m++) {
      int row = wr * 2 + (m >> 1);
      int a0 = (TAPS == 9) ? ((row + dy + 1) * PR + (m & 1) * 16 + dx + 1)
                           : (wr * 64 + m * 16);
      int a = a0 + l15;
      const char* Ab = (const char*)Ash[ab] + (size_t)a * 128;
      int sw = a & 7;
#pragma unroll
      for (int ks = 0; ks < 2; ks++)
        af[m][ks] = *(const bf8*)(Ab + (((ks * 4 + lhi) ^ sw) * 16));
    }
    const char* Bb = (const char*)Bsh[p & 1];
    bf8 bfr[2][2];
#pragma unroll
    for (int n = 0; n < 2; n++)
#pragma unroll
      for (int ks = 0; ks < 2; ks++)
        bfr[n][ks] = *(const bf8*)(Bb + (size_t)(ks * 4 + lhi) * 1024 + (size_t)(wc * 32 + n * 16 + l15) * 16);
#pragma unroll
    for (int ks = 0; ks < 2; ks++)
#pragma unroll
      for (int m = 0; m < 4; m++)
#pragma unroll
        for (int n = 0; n < 2; n++)
          acc[m][n] = mfma_bf16(af[m][ks], bfr[n][ks], acc[m][n]);
    t = tn; k0 = kn; ab = an;
  }

#pragma unroll
  for (int m = 0; m < 4; m++) {
    int pbase = p0 + wr * 64 + m * 16 + lhi * 4;
#pragma unroll
    for (int n = 0; n < 2; n++) {
      int co = co0 + wc * 32 + n * 16 + l15;
      float bv = bias[co];
      if (EPI == 4) {
        union { bf4 v; unsigned long long u; } pk4;
#pragma unroll
        for (int r = 0; r < 4; r++) pk4.v[r] = (short)f2bf(acc[m][n][r] + bv);
        *(unsigned long long*)(outb + ((size_t)b * CH_ + co) * NSP + pbase) = pk4.u;
      } else {
#pragma unroll
        for (int r = 0; r < 4; r++) {
          int p = pbase + r;
          size_t idx = ((size_t)b * NSP + p) * CH_ + co;
          float v = acc[m][n][r] + bv;
          if (EPI == 0) outf[idx] = v;
          else if (EPI == 1) outb[idx] = f2bf(v);
          else if (EPI == 3) outb[idx] = f2bf(v * 0.125f);
          else outf[idx] = v + addf[idx];
        }
      }
    }
  }
}

// ---------------- GroupNorm ----------------
// MODE 0: y = silu(gn(x))              -> outb (bf16, PADDED NHWC)
// MODE 1: y = gn(x)*(1+cond)+resid     -> outf (f32, may alias in) + outb (bf16 NHWC)
template <int MODE>
__global__ __launch_bounds__(256) void gn_kernel(
    const float* __restrict__ in, const float* __restrict__ gw, const float* __restrict__ gb,
    const float* __restrict__ cond, const float* __restrict__ resid,
    float* __restrict__ outf, u16* __restrict__ outb) {
  int b = blockIdx.y, g = blockIdx.x;
  int tid = threadIdx.x;
  int c = g * 8 + (tid & 7);
  int prow = tid >> 3;            // 0..31
  const float* base = in + (size_t)b * NSP * CH_ + c;
  float v[32];
  float s = 0.f, ss = 0.f;
#pragma unroll
  for (int i = 0; i < 32; i++) {
    v[i] = base[(size_t)(prow + i * 32) * CH_];
    s += v[i]; ss += v[i] * v[i];
  }
  __shared__ float rs[256], rss[256];
  rs[tid] = s; rss[tid] = ss;
  __syncthreads();
  for (int off = 128; off > 0; off >>= 1) {
    if (tid < off) { rs[tid] += rs[tid + off]; rss[tid] += rss[tid + off]; }
    __syncthreads();
  }
  float mean = rs[0] * (1.f / 8192.f);
  float var = rss[0] * (1.f / 8192.f) - mean * mean;
  float inv = rsqrtf(var + 1e-5f);
  float gamma = gw[c], beta = gb[c];
  float cm = 0.f;
  if (MODE == 1) cm = 1.f + cond[b * CH_ + c];
#pragma unroll
  for (int i = 0; i < 32; i++) {
    int p = prow + i * 32;
    float y = (v[i] - mean) * inv * gamma + beta;
    if (MODE == 0) {
      float sg = 1.f / (1.f + __expf(-y));
      int yy = p >> 5, xc = p & 31;
      outb[((size_t)b * PPB + (size_t)(yy + 1) * PR + xc + 1) * CH_ + c] = f2bf(y * sg);
    } else {
      size_t idx = ((size_t)b * NSP + p) * CH_ + c;
      float z = y * cm + resid[idx];
      outf[idx] = z;
      outb[idx] = f2bf(z);
    }
  }
}

// ---------------- flash attention (swapped-QK, P in registers) ----------------
// q,k bf16 NHWC [B][1024][512] (q pre-scaled by 0.125); vT bf16 [B][512][1024].
// Block: 128 q-rows, 4 waves x 32 q. K,V^T double-buffered in LDS via global_load_lds
// with chunk-XOR swizzle. S^T = mfma(K,Q) -> lane holds P[q=l15][k=kf*16+lhi*4+r];
// that register layout feeds PV's A-frag directly (slot->kpos remap matched by V reads).
__global__ __launch_bounds__(256) void attn_kernel(const u16* __restrict__ q, const u16* __restrict__ k,
                                                   const u16* __restrict__ vT, u16* __restrict__ ao) {
  int bid = blockIdx.x;
  int swz = (bid & 7) * 64 + (bid >> 3);   // XCD-bijective: each XCD owns one batch
  int b = swz >> 6;
  int head = (swz >> 3) & 7;
  int qt = swz & 7;
  int tid = threadIdx.x, lane = tid & 63, wid = tid >> 6;
  int l15 = lane & 15, lhi = lane >> 4;
  int cb = head * HD;
  int q0 = qt * 128 + wid * 32;

  const char* qp = (const char*)(q + (size_t)b * NSP * CH_ + cb);
  const char* kp = (const char*)(k + (size_t)b * NSP * CH_ + cb);
  const char* vp = (const char*)(vT + ((size_t)b * CH_ + cb) * NSP);

  __shared__ u16 Ksh[2][64 * 64];
  __shared__ u16 Vsh[2][64 * 64];

  bf8 aq[2][2];
#pragma unroll
  for (int qh = 0; qh < 2; qh++)
#pragma unroll
    for (int ks = 0; ks < 2; ks++)
      aq[qh][ks] = *(const bf8*)(qp + ((size_t)(q0 + qh * 16 + l15) * CH_ + ks * 32 + lhi * 8) * 2);

  f32x4 o[2][4];
  float mrow[2], lrow[2];
#pragma unroll
  for (int qh = 0; qh < 2; qh++) {
    mrow[qh] = -1e30f; lrow[qh] = 0.f;
#pragma unroll
    for (int n = 0; n < 4; n++) o[qh][n] = {0.f, 0.f, 0.f, 0.f};
  }

  auto stage = [&](int kt, int buf) {
#pragma unroll
    for (int t = 0; t < 2; t++) {
      int i = wid * 2 + t;
      int chunk = i * 64 + lane;             // 0..511
      int r = chunk >> 3, c = chunk & 7;
      gload16(kp + (size_t)(kt * 64 + r) * 1024 + (size_t)((c ^ (r & 7)) * 16),
              (char*)Ksh[buf] + i * 1024);
    }
#pragma unroll
    for (int t = 0; t < 2; t++) {
      int i = wid * 2 + t;
      int chunk = i * 64 + lane;
      int r = chunk >> 3, c = chunk & 7;     // r = d row of V^T
      gload16(vp + (size_t)r * 2048 + (size_t)(kt * 128) + (size_t)((c ^ (r & 7)) * 16),
              (char*)Vsh[buf] + i * 1024);
    }
  };

  stage(0, 0);

  for (int kt = 0; kt < 16; ++kt) {
    __syncthreads();
    if (kt < 15) stage(kt + 1, (kt + 1) & 1);
    const char* Kb = (const char*)Ksh[kt & 1];
    const char* Vb = (const char*)Vsh[kt & 1];

    // QK^T (swapped): sacc[qh][kf], element r <-> kpos = kf*16+lhi*4+r, q = q0+qh*16+l15
    f32x4 sacc[2][4];
#pragma unroll
    for (int qh = 0; qh < 2; qh++)
#pragma unroll
      for (int kf = 0; kf < 4; kf++) sacc[qh][kf] = {0.f, 0.f, 0.f, 0.f};

#pragma unroll
    for (int kf = 0; kf < 4; kf++) {
      bf8 ak[2];
#pragma unroll
      for (int ks = 0; ks < 2; ks++)
        ak[ks] = *(const bf8*)(Kb + (size_t)(kf * 16 + l15) * 128 + (((ks * 4 + lhi) ^ (l15 & 7)) * 16));
#pragma unroll
      for (int qh = 0; qh < 2; qh++)
#pragma unroll
        for (int ks = 0; ks < 2; ks++)
          sacc[qh][kf] = mfma_bf16(ak[ks], aq[qh][ks], sacc[qh][kf]);
    }

    // online softmax, P stays in registers as bf16 pairs
    unsigned pk[2][4][2];
#pragma unroll
    for (int qh = 0; qh < 2; qh++) {
      float pmax = sacc[qh][0][0];
#pragma unroll
      for (int kf = 0; kf < 4; kf++)
#pragma unroll
        for (int r = 0; r < 4; r++) pmax = fmaxf(pmax, sacc[qh][kf][r]);
      pmax = fmaxf(pmax, __shfl_xor(pmax, 16, 64));
      pmax = fmaxf(pmax, __shfl_xor(pmax, 32, 64));
      float mn = fmaxf(mrow[qh], pmax);
      float corr = __expf(mrow[qh] - mn);
      mrow[qh] = mn;
      float rsum = 0.f;
#pragma unroll
      for (int kf = 0; kf < 4; kf++) {
        f32x4 pv;
#pragma unroll
        for (int r = 0; r < 4; r++) {
          pv[r] = __expf(sacc[qh][kf][r] - mn);
          rsum += pv[r];
        }
        pk[qh][kf][0] = cvt_pk_bf16(pv[0], pv[1]);
        pk[qh][kf][1] = cvt_pk_bf16(pv[2], pv[3]);
      }
      rsum += __shfl_xor(rsum, 16, 64);
      rsum += __shfl_xor(rsum, 32, 64);
      lrow[qh] = lrow[qh] * corr + rsum;
      float corr_o[4];
#pragma unroll
      for (int r = 0; r < 4; r++) corr_o[r] = __shfl(corr, lhi * 4 + r, 64);
#pragma unroll
      for (int n = 0; n < 4; n++)
#pragma unroll
        for (int r = 0; r < 4; r++) o[qh][n][r] *= corr_o[r];
    }

    // PV: A = P regs (slot j -> kpos = 32g + (j>=4)*16 + 4*lhi + (j&3)); B = V^T reads matching
#pragma unroll
    for (int g = 0; g < 2; g++) {
      union { bf8 v8; unsigned u[4]; } ap[2];
#pragma unroll
      for (int qh = 0; qh < 2; qh++) {
        ap[qh].u[0] = pk[qh][2 * g][0];
        ap[qh].u[1] = pk[qh][2 * g][1];
        ap[qh].u[2] = pk[qh][2 * g + 1][0];
        ap[qh].u[3] = pk[qh][2 * g + 1][1];
      }
#pragma unroll
      for (int nf2 = 0; nf2 < 4; nf2++) {
        int row = nf2 * 16 + l15;
        int c0 = 4 * g + (lhi >> 1);
        union { bf8 v8; bf4 v4[2]; } bv;
        bv.v4[0] = *(const bf4*)(Vb + (size_t)row * 128 + ((c0 ^ (l15 & 7)) * 16) + (lhi & 1) * 8);
        bv.v4[1] = *(const bf4*)(Vb + (size_t)row * 128 + (((c0 + 2) ^ (l15 & 7)) * 16) + (lhi & 1) * 8);
#pragma unroll
        for (int qh = 0; qh < 2; qh++)
          o[qh][nf2] = mfma_bf16(ap[qh].v8, bv.v8, o[qh][nf2]);
      }
    }
  }

  // epilogue: O rows q = q0+qh*16+lhi*4+r, cols d = nf2*16+l15
#pragma unroll
  for (int qh = 0; qh < 2; qh++) {
    float linv[4];
#pragma unroll
    for (int r = 0; r < 4; r++) linv[r] = 1.f / __shfl(lrow[qh], lhi * 4 + r, 64);
#pragma unroll
    for (int nf2 = 0; nf2 < 4; nf2++)
#pragma unroll
      for (int r = 0; r < 4; r++) {
        float val = o[qh][nf2][r] * linv[r];
        ao[((size_t)b * NSP + q0 + qh * 16 + lhi * 4 + r) * CH_ + cb + nf2 * 16 + l15] = f2bf(val);
      }
  }
}

// ---------------- launch ----------------

extern "C" void kernel_launch(void* const* d_in, const int* in_sizes, int n_in,
                              void* d_out, int out_size, void* d_ws, size_t ws_size,
                              hipStream_t stream) {
  const float* x    = (const float*)d_in[0];
  const float* cnd  = (const float*)d_in[1];
  const float* c1w  = (const float*)d_in[2];
  const float* c1b  = (const float*)d_in[3];
  const float* g1w  = (const float*)d_in[4];
  const float* g1b  = (const float*)d_in[5];
  const float* c2w  = (const float*)d_in[6];
  const float* c2b  = (const float*)d_in[7];
  const float* g2w  = (const float*)d_in[8];
  const float* g2b  = (const float*)d_in[9];
  const float* cpw  = (const float*)d_in[10];
  const float* cpb  = (const float*)d_in[11];
  const float* rpw  = (const float*)d_in[12];
  const float* rpb  = (const float*)d_in[13];
  const float* qw   = (const float*)d_in[14];
  const float* qb   = (const float*)d_in[15];
  const float* kw   = (const float*)d_in[16];
  const float* kb   = (const float*)d_in[17];
  const float* vw   = (const float*)d_in[18];
  const float* vb   = (const float*)d_in[19];
  const float* ow   = (const float*)d_in[20];
  const float* ob   = (const float*)d_in[21];
  float* out = (float*)d_out;

  char* ws = (char*)d_ws;
  size_t off = 0;
  auto alloc = [&](size_t bytes) -> char* {
    char* p = ws + off;
    off = (off + bytes + 255) & ~(size_t)255;
    return p;
  };
  const size_t ACT_F = (size_t)NB * NSP * CH_ * 4;   // 16 MB
  const size_t ACT_B = (size_t)NB * NSP * CH_ * 2;   // 8 MB
  const size_t PAD_B = (size_t)NB * PPB * CH_ * 2;   // 9.47 MB

  u16* xp    = (u16*)alloc(PAD_B);               // x padded NHWC bf16
  u16* h1p   = (u16*)alloc(PAD_B);               // silu(gn1) padded bf16
  u16* w1p   = (u16*)alloc((size_t)9 * CH_ * CH_ * 2);
  u16* w2p   = (u16*)alloc((size_t)9 * CH_ * CH_ * 2);
  u16* wrp   = (u16*)alloc((size_t)CH_ * CH_ * 2);
  u16* wqp   = (u16*)alloc((size_t)CH_ * CH_ * 2);
  u16* wkp   = (u16*)alloc((size_t)CH_ * CH_ * 2);
  u16* wvp   = (u16*)alloc((size_t)CH_ * CH_ * 2);
  u16* wop   = (u16*)alloc((size_t)CH_ * CH_ * 2);
  float* cndv = (float*)alloc((size_t)NB * CH_ * 4);
  float* resid = (float*)alloc(ACT_F);           // residual; reused as final NHWC f32
  float* h12  = (float*)alloc(ACT_F);            // conv outs; gn2 in-place -> h (f32)
  u16* hb    = (u16*)alloc(ACT_B);               // h bf16 (attn input)
  u16* qbuf  = (u16*)alloc(ACT_B);               // Q (pre-scaled) NHWC bf16
  u16* kbuf  = (u16*)alloc(ACT_B);               // K NHWC bf16
  u16* vTb   = (u16*)alloc(ACT_B);               // V^T [B][512][1024] bf16
  u16* aob   = (u16*)alloc(ACT_B);               // attention out bf16
  if (off > ws_size) return;

  dim3 tgrid(NSP / 32, CH_ / 32, NB);
  border_zero_kernel<<<(NB * 132 * 64 + 255) / 256, 256, 0, stream>>>(xp, h1p);
  pack_x_kernel<<<tgrid, 1024, 0, stream>>>(x, xp);
  pack_w3_kernel<<<(9 * 64 * CH_ + 255) / 256, 256, 0, stream>>>(c1w, w1p);
  pack_w3_kernel<<<(9 * 64 * CH_ + 255) / 256, 256, 0, stream>>>(c2w, w2p);
  pack_w1_kernel<<<(64 * CH_) / 256, 256, 0, stream>>>(rpw, wrp);
  pack_w1_kernel<<<(64 * CH_) / 256, 256, 0, stream>>>(qw, wqp);
  pack_w1_kernel<<<(64 * CH_) / 256, 256, 0, stream>>>(kw, wkp);
  pack_w1_kernel<<<(64 * CH_) / 256, 256, 0, stream>>>(vw, wvp);
  pack_w1_kernel<<<(64 * CH_) / 256, 256, 0, stream>>>(ow, wop);
  cond_kernel<<<dim3(CH_ / 4, NB), 256, 0, stream>>>(cnd, cpw, cpb, cndv);

  dim3 ggrid(NSP / 128, CH_ / 64, NB);
  // conv1 (3x3, padded in) -> h12 f32 ; residual proj (1x1, padded in) -> resid f32
  conv_kernel<9, 1, 0><<<ggrid, 256, 0, stream>>>(xp, w1p, c1b, h12, nullptr, nullptr);
  conv_kernel<1, 1, 0><<<ggrid, 256, 0, stream>>>(xp, wrp, rpb, resid, nullptr, nullptr);
  // gn1 + silu -> h1p (padded bf16)
  gn_kernel<0><<<dim3(NGROUP, NB), 256, 0, stream>>>(h12, g1w, g1b, nullptr, nullptr, nullptr, h1p);
  // conv2 (3x3, padded in) -> h12 f32
  conv_kernel<9, 1, 0><<<ggrid, 256, 0, stream>>>(h1p, w2p, c2b, h12, nullptr, nullptr);
  // gn2 * (1+cond) + resid -> h12 (in-place f32), hb bf16
  gn_kernel<1><<<dim3(NGROUP, NB), 256, 0, stream>>>(h12, g2w, g2b, cndv, resid, h12, hb);
  // q (pre-scaled), k, v^T (1x1) -> bf16
  conv_kernel<1, 0, 3><<<ggrid, 256, 0, stream>>>(hb, wqp, qb, nullptr, qbuf, nullptr);
  conv_kernel<1, 0, 1><<<ggrid, 256, 0, stream>>>(hb, wkp, kb, nullptr, kbuf, nullptr);
  conv_kernel<1, 0, 4><<<ggrid, 256, 0, stream>>>(hb, wvp, vb, nullptr, vTb, nullptr);
  // attention -> aob bf16 NHWC
  attn_kernel<<<512, 256, 0, stream>>>(qbuf, kbuf, vTb, aob);
  // out proj + h -> resid (NHWC f32), then transpose to NCHW d_out
  conv_kernel<1, 0, 2><<<ggrid, 256, 0, stream>>>(aob, wop, ob, resid, nullptr, h12);
  transpose_out_kernel<<<tgrid, 1024, 0, stream>>>(resid, out);
}

// Round 5
// 259.265 us; speedup vs baseline: 2.2652x; 1.1735x over previous
//
#include <hip/hip_runtime.h>
#include <hip/hip_bf16.h>

typedef unsigned short u16;
typedef __attribute__((ext_vector_type(8))) short bf8;   // 8 bf16 (raw bits, 4 VGPRs)
typedef __attribute__((ext_vector_type(4))) short bf4;   // 4 bf16 (2 VGPRs)
typedef __attribute__((ext_vector_type(4))) float f32x4;

#define CH_ 512
#define NSP 1024      // 32*32 spatial
#define NB 8
#define CONDDIM 1280
#define NGROUP 64     // 512/8
#define HEADS_ 8
#define HD 64         // head dim
#define PR 34         // padded row length (32 + 2)
#define PPB (PR*PR)   // padded positions per batch = 1156

#define VWAIT(N) asm volatile("s_waitcnt vmcnt(" #N ")" ::: "memory")
#define SCHEDB __builtin_amdgcn_sched_barrier(0)
#define BARRIER do { SCHEDB; __builtin_amdgcn_s_barrier(); SCHEDB; } while (0)

__device__ __forceinline__ u16 f2bf(float f) {
  union { float f; unsigned u; } v; v.f = f;
  unsigned u = v.u;
  return (u16)((u + 0x7fffu + ((u >> 16) & 1u)) >> 16);   // RNE
}

__device__ __forceinline__ unsigned cvt_pk_bf16(float lo, float hi) {
  unsigned r;
  asm volatile("v_cvt_pk_bf16_f32 %0, %1, %2" : "=v"(r) : "v"(lo), "v"(hi));
  return r;
}

__device__ __forceinline__ f32x4 mfma_bf16(bf8 a, bf8 b, f32x4 c) {
  return __builtin_amdgcn_mfma_f32_16x16x32_bf16(a, b, c, 0, 0, 0);
}

__device__ __forceinline__ void gload16(const void* g, void* l) {
  __builtin_amdgcn_global_load_lds((const __attribute__((address_space(1))) void*)g,
                                   (__attribute__((address_space(3))) void*)l, 16, 0, 0);
}

// ---------------- pack / transpose kernels ----------------

// x: NCHW f32 -> xp: padded NHWC bf16 [B][34][34][512] (interior only)
__global__ __launch_bounds__(1024) void pack_x_kernel(const float* __restrict__ x, u16* __restrict__ xp) {
  __shared__ float t[32][33];
  int b = blockIdx.z;
  int c0 = blockIdx.y * 32, p0 = blockIdx.x * 32;
  int tx = threadIdx.x & 31, ty = threadIdx.x >> 5;
  t[ty][tx] = x[((size_t)b * CH_ + c0 + ty) * NSP + p0 + tx];
  __syncthreads();
  int p = p0 + ty;
  int y = p >> 5, xc = p & 31;
  xp[((size_t)b * PPB + (size_t)(y + 1) * PR + xc + 1) * CH_ + c0 + tx] = f2bf(t[tx][ty]);
}

// zero the borders of two padded bf16 buffers
__global__ __launch_bounds__(256) void border_zero_kernel(u16* __restrict__ a, u16* __restrict__ b) {
  int id = blockIdx.x * 256 + threadIdx.x;   // (b, border-pos, ch-chunk of 8)
  if (id >= NB * 132 * 64) return;
  int ch8 = id & 63;
  int rest = id >> 6;
  int bidx = rest % 132;
  int bb = rest / 132;
  int r, c;
  if (bidx < 34)       { r = 0;          c = bidx; }
  else if (bidx < 68)  { r = 33;         c = bidx - 34; }
  else if (bidx < 100) { r = bidx - 67;  c = 0; }
  else                 { r = bidx - 99;  c = 33; }
  size_t off = ((size_t)bb * PPB + (size_t)r * PR + c) * CH_ + ch8 * 8;
  const bf8 z = {0, 0, 0, 0, 0, 0, 0, 0};
  *(bf8*)(a + off) = z;
  *(bf8*)(b + off) = z;
}

// 3x3 weights [co][ci][3][3] f32 -> packed [t][ci/8][co][8] bf16
__global__ __launch_bounds__(256) void pack_w3_kernel(const float* __restrict__ w, u16* __restrict__ wp) {
  int id = blockIdx.x * 256 + threadIdx.x;        // (t, cib, co)
  if (id >= 9 * 64 * CH_) return;
  int co = id & (CH_ - 1);
  int cib = (id >> 9) & 63;
  int t = id >> 15;
  int dy = t / 3, dx = t % 3;
  bf8 v;
#pragma unroll
  for (int j = 0; j < 8; j++) {
    int ci = cib * 8 + j;
    v[j] = (short)f2bf(w[(((size_t)co * CH_ + ci) * 3 + dy) * 3 + dx]);
  }
  *(bf8*)(wp + ((size_t)(t * 64 + cib) * CH_ + co) * 8) = v;
}

// 1x1 weights [co][ci] f32 -> packed [ci/8][co][8] bf16
__global__ __launch_bounds__(256) void pack_w1_kernel(const float* __restrict__ w, u16* __restrict__ wp) {
  int id = blockIdx.x * 256 + threadIdx.x;        // (cib, co)
  if (id >= 64 * CH_) return;
  int co = id & (CH_ - 1);
  int cib = id >> 9;
  bf8 v;
#pragma unroll
  for (int j = 0; j < 8; j++) v[j] = (short)f2bf(w[(size_t)co * CH_ + cib * 8 + j]);
  *(bf8*)(wp + ((size_t)cib * CH_ + co) * 8) = v;
}

// cond[b][c] = conditioning[b] . cpw[c] + cpb[c]   (f32)
__global__ __launch_bounds__(256) void cond_kernel(const float* __restrict__ cd, const float* __restrict__ cpw,
                                                   const float* __restrict__ cpb, float* __restrict__ cond) {
  int b = blockIdx.y;
  int c = blockIdx.x * 4 + (threadIdx.x >> 6);
  int lane = threadIdx.x & 63;
  const float* wrow = cpw + (size_t)c * CONDDIM;
  const float* crow = cd + (size_t)b * CONDDIM;
  float s = 0.f;
  for (int i = lane; i < CONDDIM; i += 64) s += crow[i] * wrow[i];
#pragma unroll
  for (int m = 32; m > 0; m >>= 1) s += __shfl_xor(s, m, 64);
  if (lane == 0) cond[b * CH_ + c] = s + cpb[c];
}

// ---------------- counted-vmcnt implicit-GEMM conv ----------------
// K-step 32, linear LDS (64B rows), staging 2 phases ahead, per-phase
// s_waitcnt vmcnt(N) + raw s_barrier (loads never drained to 0 in the loop).
// Tile 128 pos x 64 co, 4 waves (2 pos x 2 co), 8 MFMA/phase.
// EPI: 0 = f32 NHWC (+bias); 2 = FINAL f32 NCHW vectorized (+bias+addf NHWC);
//      5 = QKV fused (seg = blockIdx.y>>3: q bf16*0.125 / k bf16 / vT bf16)
template <int TAPS, int PIN, int EPI>
__global__ __launch_bounds__(256, TAPS == 9 ? 4 : 3) void conv_kernel(
    const u16* __restrict__ in, const u16* __restrict__ wp, const float* __restrict__ bias,
    float* __restrict__ outf, const float* __restrict__ addf,
    u16* __restrict__ o0, u16* __restrict__ o1, u16* __restrict__ o2,
    const float* __restrict__ b0, const float* __restrict__ b1, const float* __restrict__ b2) {
  constexpr int LDSZ = (TAPS == 9) ? (2 * 14336 + 3 * 4096) : (4 * 8192 + 4 * 4096);
  __shared__ char lds[LDSZ];
  char* ldsA = lds;
  char* ldsB = lds + ((TAPS == 9) ? 2 * 14336 : 4 * 8192);

  const int b = blockIdx.z;
  int seg = 0, coy = blockIdx.y;
  if constexpr (EPI == 5) { seg = coy >> 3; coy &= 7; }
  const int co0 = coy * 64;
  const int p0 = blockIdx.x * 128;
  const int tid = threadIdx.x;
  const int lane = tid & 63, wid = tid >> 6;
  const int wv = wid >> 1, wc = wid & 1;
  const int l15 = lane & 15, lhi = lane >> 4;

  // global bases
  const char* aSrc;
  if constexpr (TAPS == 9) {
    aSrc = (const char*)in + ((size_t)b * PPB + (size_t)blockIdx.x * 4 * PR) * 1024;
  } else if constexpr (PIN) {
    aSrc = (const char*)in + (size_t)b * PPB * 1024;
  } else {
    aSrc = (const char*)in + ((size_t)b * NSP + p0) * 1024;
  }
  const char* bSrc = (const char*)wp + (size_t)((EPI == 5) ? seg * 524288 : 0) + co0 * 16;

  // per-thread staging source offsets
  const int pB = ((tid >> 6) * 512 + (tid & 63)) * 16;
  int pA0, pA1, pA3 = 0;
  if constexpr (TAPS == 9) {
    pA0 = ((tid >> 2) << 10) + ((tid & 3) << 4);                       // iters j: + j*65536
    pA3 = ((192 + ((tid & 127) >> 2)) << 10) + ((tid & 3) << 4);       // iter 3 (dup waves 2,3)
    pA1 = 0;
  } else {
    int a0 = (tid >> 2), a1 = 64 + (tid >> 2);
    if constexpr (PIN) {
      int pp0 = p0 + a0, pp1 = p0 + a1;
      int g0 = ((pp0 >> 5) + 1) * PR + (pp0 & 31) + 1;
      int g1 = ((pp1 >> 5) + 1) * PR + (pp1 & 31) + 1;
      pA0 = (g0 << 10) + ((tid & 3) << 4);
      pA1 = (g1 << 10) + ((tid & 3) << 4);
    } else {
      pA0 = (a0 << 10) + ((tid & 3) << 4);
      pA1 = (a1 << 10) + ((tid & 3) << 4);
    }
  }

  // per-thread LDS read bases
  const int aAddr = (TAPS == 9) ? ((wv * 68 + l15) * 64 + lhi * 16)
                                : ((wv * 64 + l15) * 64 + lhi * 16);
  const int bAddr = (lhi * 64 + wc * 32 + l15) * 16;

  f32x4 acc[4][2];
#pragma unroll
  for (int m = 0; m < 4; m++)
#pragma unroll
    for (int n = 0; n < 2; n++) acc[m][n] = {0.f, 0.f, 0.f, 0.f};

  if constexpr (TAPS == 9) {
    // ---- prologue: A(kc0) fully + B(t0) + B(t1) ----
    gload16(aSrc + pA0,          ldsA + (wid << 10));
    gload16(aSrc + pA0 + 65536,  ldsA + 4096 + (wid << 10));
    gload16(aSrc + pA0 + 131072, ldsA + 8192 + (wid << 10));
    gload16(aSrc + pA3,          ldsA + 12288 + ((wid & 1) << 10));
    gload16(bSrc + pB,           ldsB + (wid << 10));            // (t0,kc0) -> slot 0
    gload16(bSrc + 524288 + pB,  ldsB + 4096 + (wid << 10));     // (t1,kc0) -> slot 1  [(1*64+0)*8192]
    VWAIT(1);
    BARRIER;

#define PH9(KC, T, AS) do {                                                             \
    constexpr int DT = ((T) / 3) * 34 + ((T) % 3);                                      \
    const int kcn_ = ((KC) < 15) ? (KC) + 1 : 15;                                       \
    { const int kb_ = ((T) >= 7) ? kcn_ : (KC);                                         \
      constexpr int TB = ((T) + 2) % 9;                                                 \
      gload16(bSrc + (size_t)(TB * 64 + kb_ * 4) * 8192 + pB,                           \
              ldsB + (((T) + 2) % 3) * 4096 + (wid << 10)); }                           \
    if constexpr ((T) >= 4 && (T) < 7)                                                  \
      gload16(aSrc + kcn_ * 64 + pA0 + ((T) - 4) * 65536,                               \
              ldsA + (1 - (AS)) * 14336 + ((T) - 4) * 4096 + (wid << 10));              \
    if constexpr ((T) == 7)                                                             \
      gload16(aSrc + kcn_ * 64 + pA3,                                                   \
              ldsA + (1 - (AS)) * 14336 + 12288 + ((wid & 1) << 10));                   \
    SCHEDB;                                                                             \
    bf8 af0 = *(const bf8*)(ldsA + (AS) * 14336 + DT * 64 + 0    + aAddr);              \
    bf8 af1 = *(const bf8*)(ldsA + (AS) * 14336 + DT * 64 + 1024 + aAddr);              \
    bf8 af2 = *(const bf8*)(ldsA + (AS) * 14336 + DT * 64 + 2176 + aAddr);              \
    bf8 af3 = *(const bf8*)(ldsA + (AS) * 14336 + DT * 64 + 3200 + aAddr);              \
    bf8 bq0 = *(const bf8*)(ldsB + ((T) % 3) * 4096 + 0   + bAddr);                     \
    bf8 bq1 = *(const bf8*)(ldsB + ((T) % 3) * 4096 + 256 + bAddr);                     \
    __builtin_amdgcn_s_setprio(1);                                                      \
    acc[0][0] = mfma_bf16(af0, bq0, acc[0][0]);                                         \
    acc[0][1] = mfma_bf16(af0, bq1, acc[0][1]);                                         \
    acc[1][0] = mfma_bf16(af1, bq0, acc[1][0]);                                         \
    acc[1][1] = mfma_bf16(af1, bq1, acc[1][1]);                                         \
    acc[2][0] = mfma_bf16(af2, bq0, acc[2][0]);                                         \
    acc[2][1] = mfma_bf16(af2, bq1, acc[2][1]);                                         \
    acc[3][0] = mfma_bf16(af3, bq0, acc[3][0]);                                         \
    acc[3][1] = mfma_bf16(af3, bq1, acc[3][1]);                                         \
    __builtin_amdgcn_s_setprio(0);                                                      \
    if constexpr ((T) >= 4 && (T) <= 7) { VWAIT(2); } else { VWAIT(1); }                \
    BARRIER;                                                                            \
  } while (0)

    for (int kc2 = 0; kc2 < 8; kc2++) {
      PH9(kc2 * 2, 0, 0); PH9(kc2 * 2, 1, 0); PH9(kc2 * 2, 2, 0);
      PH9(kc2 * 2, 3, 0); PH9(kc2 * 2, 4, 0); PH9(kc2 * 2, 5, 0);
      PH9(kc2 * 2, 6, 0); PH9(kc2 * 2, 7, 0); PH9(kc2 * 2, 8, 0);
      PH9(kc2 * 2 + 1, 0, 1); PH9(kc2 * 2 + 1, 1, 1); PH9(kc2 * 2 + 1, 2, 1);
      PH9(kc2 * 2 + 1, 3, 1); PH9(kc2 * 2 + 1, 4, 1); PH9(kc2 * 2 + 1, 5, 1);
      PH9(kc2 * 2 + 1, 6, 1); PH9(kc2 * 2 + 1, 7, 1); PH9(kc2 * 2 + 1, 8, 1);
    }
#undef PH9
  } else {
    // ---- prologue: A(0),B(0) then A(1),B(1) ----
    gload16(aSrc + pA0,         ldsA + (wid << 10));
    gload16(aSrc + pA1,         ldsA + 4096 + (wid << 10));
    gload16(bSrc + pB,          ldsB + (wid << 10));
    gload16(aSrc + 64 + pA0,    ldsA + 8192 + (wid << 10));
    gload16(aSrc + 64 + pA1,    ldsA + 8192 + 4096 + (wid << 10));
    gload16(bSrc + 32768 + pB,  ldsB + 4096 + (wid << 10));
    VWAIT(3);
    BARRIER;

#define PH1(KC, S) do {                                                                 \
    constexpr int S2 = ((S) + 2) & 3;                                                   \
    const int kcn_ = ((KC) + 2 < 16) ? (KC) + 2 : 15;                                   \
    gload16(bSrc + (size_t)kcn_ * 32768 + pB, ldsB + S2 * 4096 + (wid << 10));          \
    gload16(aSrc + kcn_ * 64 + pA0, ldsA + S2 * 8192 + (wid << 10));                    \
    gload16(aSrc + kcn_ * 64 + pA1, ldsA + S2 * 8192 + 4096 + (wid << 10));             \
    SCHEDB;                                                                             \
    bf8 af0 = *(const bf8*)(ldsA + (S) * 8192 + 0    + aAddr);                          \
    bf8 af1 = *(const bf8*)(ldsA + (S) * 8192 + 1024 + aAddr);                          \
    bf8 af2 = *(const bf8*)(ldsA + (S) * 8192 + 2048 + aAddr);                          \
    bf8 af3 = *(const bf8*)(ldsA + (S) * 8192 + 3072 + aAddr);                          \
    bf8 bq0 = *(const bf8*)(ldsB + (S) * 4096 + 0   + bAddr);                           \
    bf8 bq1 = *(const bf8*)(ldsB + (S) * 4096 + 256 + bAddr);                           \
    __builtin_amdgcn_s_setprio(1);                                                      \
    acc[0][0] = mfma_bf16(af0, bq0, acc[0][0]);                                         \
    acc[0][1] = mfma_bf16(af0, bq1, acc[0][1]);                                         \
    acc[1][0] = mfma_bf16(af1, bq0, acc[1][0]);                                         \
    acc[1][1] = mfma_bf16(af1, bq1, acc[1][1]);                                         \
    acc[2][0] = mfma_bf16(af2, bq0, acc[2][0]);                                         \
    acc[2][1] = mfma_bf16(af2, bq1, acc[2][1]);                                         \
    acc[3][0] = mfma_bf16(af3, bq0, acc[3][0]);                                         \
    acc[3][1] = mfma_bf16(af3, bq1, acc[3][1]);                                         \
    __builtin_amdgcn_s_setprio(0);                                                      \
    VWAIT(3);                                                                           \
    BARRIER;                                                                            \
  } while (0)

    for (int kc4 = 0; kc4 < 4; kc4++) {
      PH1(kc4 * 4 + 0, 0); PH1(kc4 * 4 + 1, 1); PH1(kc4 * 4 + 2, 2); PH1(kc4 * 4 + 3, 3);
    }
#undef PH1
  }

  VWAIT(0);   // drain stray prefetches before LDS teardown

  // ---- epilogue ----
#pragma unroll
  for (int m = 0; m < 4; m++) {
    int pbase = p0 + wv * 64 + m * 16 + lhi * 4;
#pragma unroll
    for (int n = 0; n < 2; n++) {
      int co = co0 + wc * 32 + n * 16 + l15;
      if constexpr (EPI == 0) {
        float bv = bias[co];
#pragma unroll
        for (int r = 0; r < 4; r++)
          outf[((size_t)b * NSP + pbase + r) * CH_ + co] = acc[m][n][r] + bv;
      } else if constexpr (EPI == 2) {
        float bv = bias[co];
        f32x4 v;
#pragma unroll
        for (int r = 0; r < 4; r++)
          v[r] = acc[m][n][r] + bv + addf[((size_t)b * NSP + pbase + r) * CH_ + co];
        *(f32x4*)(outf + ((size_t)b * CH_ + co) * NSP + pbase) = v;
      } else {  // EPI == 5 (qkv)
        if (seg == 0) {
          float bv = b0[co];
#pragma unroll
          for (int r = 0; r < 4; r++)
            o0[((size_t)b * NSP + pbase + r) * CH_ + co] = f2bf((acc[m][n][r] + bv) * 0.125f);
        } else if (seg == 1) {
          float bv = b1[co];
#pragma unroll
          for (int r = 0; r < 4; r++)
            o1[((size_t)b * NSP + pbase + r) * CH_ + co] = f2bf(acc[m][n][r] + bv);
        } else {
          float bv = b2[co];
          union { bf4 v; unsigned long long u; } pk4;
#pragma unroll
          for (int r = 0; r < 4; r++) pk4.v[r] = (short)f2bf(acc[m][n][r] + bv);
          *(unsigned long long*)(o2 + ((size_t)b * CH_ + co) * NSP + pbase) = pk4.u;
        }
      }
    }
  }
}

// ---------------- GroupNorm ----------------
// MODE 0: y = silu(gn(x))              -> outb (bf16, PADDED NHWC)
// MODE 1: y = gn(x)*(1+cond)+resid     -> outf (f32, may alias in) + outb (bf16 NHWC)
template <int MODE>
__global__ __launch_bounds__(256) void gn_kernel(
    const float* __restrict__ in, const float* __restrict__ gw, const float* __restrict__ gb,
    const float* __restrict__ cond, const float* __restrict__ resid,
    float* __restrict__ outf, u16* __restrict__ outb) {
  int b = blockIdx.y, g = blockIdx.x;
  int tid = threadIdx.x;
  int c = g * 8 + (tid & 7);
  int prow = tid >> 3;            // 0..31
  const float* base = in + (size_t)b * NSP * CH_ + c;
  float v[32];
  float s = 0.f, ss = 0.f;
#pragma unroll
  for (int i = 0; i < 32; i++) {
    v[i] = base[(size_t)(prow + i * 32) * CH_];
    s += v[i]; ss += v[i] * v[i];
  }
  __shared__ float rs[256], rss[256];
  rs[tid] = s; rss[tid] = ss;
  __syncthreads();
  for (int off = 128; off > 0; off >>= 1) {
    if (tid < off) { rs[tid] += rs[tid + off]; rss[tid] += rss[tid + off]; }
    __syncthreads();
  }
  float mean = rs[0] * (1.f / 8192.f);
  float var = rss[0] * (1.f / 8192.f) - mean * mean;
  float inv = rsqrtf(var + 1e-5f);
  float gamma = gw[c], beta = gb[c];
  float cm = 0.f;
  if (MODE == 1) cm = 1.f + cond[b * CH_ + c];
#pragma unroll
  for (int i = 0; i < 32; i++) {
    int p = prow + i * 32;
    float y = (v[i] - mean) * inv * gamma + beta;
    if (MODE == 0) {
      float sg = 1.f / (1.f + __expf(-y));
      int yy = p >> 5, xc = p & 31;
      outb[((size_t)b * PPB + (size_t)(yy + 1) * PR + xc + 1) * CH_ + c] = f2bf(y * sg);
    } else {
      size_t idx = ((size_t)b * NSP + p) * CH_ + c;
      float z = y * cm + resid[idx];
      outf[idx] = z;
      outb[idx] = f2bf(z);
    }
  }
}

// ---------------- flash attention (swapped-QK, P in registers) ----------------
__global__ __launch_bounds__(256) void attn_kernel(const u16* __restrict__ q, const u16* __restrict__ k,
                                                   const u16* __restrict__ vT, u16* __restrict__ ao) {
  int bid = blockIdx.x;
  int swz = (bid & 7) * 64 + (bid >> 3);   // XCD-bijective: each XCD owns one batch
  int b = swz >> 6;
  int head = (swz >> 3) & 7;
  int qt = swz & 7;
  int tid = threadIdx.x, lane = tid & 63, wid = tid >> 6;
  int l15 = lane & 15, lhi = lane >> 4;
  int cb = head * HD;
  int q0 = qt * 128 + wid * 32;

  const char* qp = (const char*)(q + (size_t)b * NSP * CH_ + cb);
  const char* kp = (const char*)(k + (size_t)b * NSP * CH_ + cb);
  const char* vp = (const char*)(vT + ((size_t)b * CH_ + cb) * NSP);

  __shared__ u16 Ksh[2][64 * 64];
  __shared__ u16 Vsh[2][64 * 64];

  bf8 aq[2][2];
#pragma unroll
  for (int qh = 0; qh < 2; qh++)
#pragma unroll
    for (int ks = 0; ks < 2; ks++)
      aq[qh][ks] = *(const bf8*)(qp + ((size_t)(q0 + qh * 16 + l15) * CH_ + ks * 32 + lhi * 8) * 2);

  f32x4 o[2][4];
  float mrow[2], lrow[2];
#pragma unroll
  for (int qh = 0; qh < 2; qh++) {
    mrow[qh] = -1e30f; lrow[qh] = 0.f;
#pragma unroll
    for (int n = 0; n < 4; n++) o[qh][n] = {0.f, 0.f, 0.f, 0.f};
  }

  auto stage = [&](int kt, int buf) {
#pragma unroll
    for (int t = 0; t < 2; t++) {
      int i = wid * 2 + t;
      int chunk = i * 64 + lane;             // 0..511
      int r = chunk >> 3, c = chunk & 7;
      gload16(kp + (size_t)(kt * 64 + r) * 1024 + (size_t)((c ^ (r & 7)) * 16),
              (char*)Ksh[buf] + i * 1024);
    }
#pragma unroll
    for (int t = 0; t < 2; t++) {
      int i = wid * 2 + t;
      int chunk = i * 64 + lane;
      int r = chunk >> 3, c = chunk & 7;     // r = d row of V^T
      gload16(vp + (size_t)r * 2048 + (size_t)(kt * 128) + (size_t)((c ^ (r & 7)) * 16),
              (char*)Vsh[buf] + i * 1024);
    }
  };

  stage(0, 0);

  for (int kt = 0; kt < 16; ++kt) {
    __syncthreads();
    if (kt < 15) stage(kt + 1, (kt + 1) & 1);
    const char* Kb = (const char*)Ksh[kt & 1];
    const char* Vb = (const char*)Vsh[kt & 1];

    f32x4 sacc[2][4];
#pragma unroll
    for (int qh = 0; qh < 2; qh++)
#pragma unroll
      for (int kf = 0; kf < 4; kf++) sacc[qh][kf] = {0.f, 0.f, 0.f, 0.f};

#pragma unroll
    for (int kf = 0; kf < 4; kf++) {
      bf8 ak[2];
#pragma unroll
      for (int ks = 0; ks < 2; ks++)
        ak[ks] = *(const bf8*)(Kb + (size_t)(kf * 16 + l15) * 128 + (((ks * 4 + lhi) ^ (l15 & 7)) * 16));
#pragma unroll
      for (int qh = 0; qh < 2; qh++)
#pragma unroll
        for (int ks = 0; ks < 2; ks++)
          sacc[qh][kf] = mfma_bf16(ak[ks], aq[qh][ks], sacc[qh][kf]);
    }

    unsigned pk[2][4][2];
#pragma unroll
    for (int qh = 0; qh < 2; qh++) {
      float pmax = sacc[qh][0][0];
#pragma unroll
      for (int kf = 0; kf < 4; kf++)
#pragma unroll
        for (int r = 0; r < 4; r++) pmax = fmaxf(pmax, sacc[qh][kf][r]);
      pmax = fmaxf(pmax, __shfl_xor(pmax, 16, 64));
      pmax = fmaxf(pmax, __shfl_xor(pmax, 32, 64));
      float mn = fmaxf(mrow[qh], pmax);
      float corr = __expf(mrow[qh] - mn);
      mrow[qh] = mn;
      float rsum = 0.f;
#pragma unroll
      for (int kf = 0; kf < 4; kf++) {
        f32x4 pv;
#pragma unroll
        for (int r = 0; r < 4; r++) {
          pv[r] = __expf(sacc[qh][kf][r] - mn);
          rsum += pv[r];
        }
        pk[qh][kf][0] = cvt_pk_bf16(pv[0], pv[1]);
        pk[qh][kf][1] = cvt_pk_bf16(pv[2], pv[3]);
      }
      rsum += __shfl_xor(rsum, 16, 64);
      rsum += __shfl_xor(rsum, 32, 64);
      lrow[qh] = lrow[qh] * corr + rsum;
      float corr_o[4];
#pragma unroll
      for (int r = 0; r < 4; r++) corr_o[r] = __shfl(corr, lhi * 4 + r, 64);
#pragma unroll
      for (int n = 0; n < 4; n++)
#pragma unroll
        for (int r = 0; r < 4; r++) o[qh][n][r] *= corr_o[r];
    }

#pragma unroll
    for (int g = 0; g < 2; g++) {
      union { bf8 v8; unsigned u[4]; } ap[2];
#pragma unroll
      for (int qh = 0; qh < 2; qh++) {
        ap[qh].u[0] = pk[qh][2 * g][0];
        ap[qh].u[1] = pk[qh][2 * g][1];
        ap[qh].u[2] = pk[qh][2 * g + 1][0];
        ap[qh].u[3] = pk[qh][2 * g + 1][1];
      }
#pragma unroll
      for (int nf2 = 0; nf2 < 4; nf2++) {
        int row = nf2 * 16 + l15;
        int c0 = 4 * g + (lhi >> 1);
        union { bf8 v8; bf4 v4[2]; } bv;
        bv.v4[0] = *(const bf4*)(Vb + (size_t)row * 128 + ((c0 ^ (l15 & 7)) * 16) + (lhi & 1) * 8);
        bv.v4[1] = *(const bf4*)(Vb + (size_t)row * 128 + (((c0 + 2) ^ (l15 & 7)) * 16) + (lhi & 1) * 8);
#pragma unroll
        for (int qh = 0; qh < 2; qh++)
          o[qh][nf2] = mfma_bf16(ap[qh].v8, bv.v8, o[qh][nf2]);
      }
    }
  }

#pragma unroll
  for (int qh = 0; qh < 2; qh++) {
    float linv[4];
#pragma unroll
    for (int r = 0; r < 4; r++) linv[r] = 1.f / __shfl(lrow[qh], lhi * 4 + r, 64);
#pragma unroll
    for (int nf2 = 0; nf2 < 4; nf2++)
#pragma unroll
      for (int r = 0; r < 4; r++) {
        float val = o[qh][nf2][r] * linv[r];
        ao[((size_t)b * NSP + q0 + qh * 16 + lhi * 4 + r) * CH_ + cb + nf2 * 16 + l15] = f2bf(val);
      }
  }
}

// ---------------- launch ----------------

extern "C" void kernel_launch(void* const* d_in, const int* in_sizes, int n_in,
                              void* d_out, int out_size, void* d_ws, size_t ws_size,
                              hipStream_t stream) {
  const float* x    = (const float*)d_in[0];
  const float* cnd  = (const float*)d_in[1];
  const float* c1w  = (const float*)d_in[2];
  const float* c1b  = (const float*)d_in[3];
  const float* g1w  = (const float*)d_in[4];
  const float* g1b  = (const float*)d_in[5];
  const float* c2w  = (const float*)d_in[6];
  const float* c2b  = (const float*)d_in[7];
  const float* g2w  = (const float*)d_in[8];
  const float* g2b  = (const float*)d_in[9];
  const float* cpw  = (const float*)d_in[10];
  const float* cpb  = (const float*)d_in[11];
  const float* rpw  = (const float*)d_in[12];
  const float* rpb  = (const float*)d_in[13];
  const float* qw   = (const float*)d_in[14];
  const float* qb   = (const float*)d_in[15];
  const float* kw   = (const float*)d_in[16];
  const float* kb   = (const float*)d_in[17];
  const float* vw   = (const float*)d_in[18];
  const float* vb   = (const float*)d_in[19];
  const float* ow   = (const float*)d_in[20];
  const float* ob   = (const float*)d_in[21];
  float* out = (float*)d_out;

  char* ws = (char*)d_ws;
  size_t off = 0;
  auto alloc = [&](size_t bytes) -> char* {
    char* p = ws + off;
    off = (off + bytes + 255) & ~(size_t)255;
    return p;
  };
  const size_t ACT_F = (size_t)NB * NSP * CH_ * 4;   // 16 MB
  const size_t ACT_B = (size_t)NB * NSP * CH_ * 2;   // 8 MB
  const size_t PAD_B = (size_t)NB * PPB * CH_ * 2;   // 9.47 MB

  u16* xp    = (u16*)alloc(PAD_B);               // x padded NHWC bf16
  u16* h1p   = (u16*)alloc(PAD_B);               // silu(gn1) padded bf16
  u16* w1p   = (u16*)alloc((size_t)9 * CH_ * CH_ * 2);
  u16* w2p   = (u16*)alloc((size_t)9 * CH_ * CH_ * 2);
  u16* wrp   = (u16*)alloc((size_t)CH_ * CH_ * 2);
  u16* wqkv  = (u16*)alloc((size_t)3 * CH_ * CH_ * 2);
  u16* wop   = (u16*)alloc((size_t)CH_ * CH_ * 2);
  float* cndv = (float*)alloc((size_t)NB * CH_ * 4);
  float* resid = (float*)alloc(ACT_F);           // residual f32 NHWC
  float* h12  = (float*)alloc(ACT_F);            // conv outs; gn2 in-place -> h (f32)
  u16* hb    = (u16*)alloc(ACT_B);               // h bf16 (attn input)
  u16* qbuf  = (u16*)alloc(ACT_B);               // Q (pre-scaled) NHWC bf16
  u16* kbuf  = (u16*)alloc(ACT_B);               // K NHWC bf16
  u16* vTb   = (u16*)alloc(ACT_B);               // V^T [B][512][1024] bf16
  u16* aob   = (u16*)alloc(ACT_B);               // attention out bf16
  if (off > ws_size) return;

  dim3 tgrid(NSP / 32, CH_ / 32, NB);
  border_zero_kernel<<<(NB * 132 * 64 + 255) / 256, 256, 0, stream>>>(xp, h1p);
  pack_x_kernel<<<tgrid, 1024, 0, stream>>>(x, xp);
  pack_w3_kernel<<<(9 * 64 * CH_ + 255) / 256, 256, 0, stream>>>(c1w, w1p);
  pack_w3_kernel<<<(9 * 64 * CH_ + 255) / 256, 256, 0, stream>>>(c2w, w2p);
  pack_w1_kernel<<<(64 * CH_) / 256, 256, 0, stream>>>(rpw, wrp);
  pack_w1_kernel<<<(64 * CH_) / 256, 256, 0, stream>>>(qw, wqkv);
  pack_w1_kernel<<<(64 * CH_) / 256, 256, 0, stream>>>(kw, wqkv + (size_t)CH_ * CH_);
  pack_w1_kernel<<<(64 * CH_) / 256, 256, 0, stream>>>(vw, wqkv + (size_t)2 * CH_ * CH_);
  pack_w1_kernel<<<(64 * CH_) / 256, 256, 0, stream>>>(ow, wop);
  cond_kernel<<<dim3(CH_ / 4, NB), 256, 0, stream>>>(cnd, cpw, cpb, cndv);

  dim3 ggrid(NSP / 128, CH_ / 64, NB);
  dim3 qgrid(NSP / 128, 3 * CH_ / 64, NB);
  // conv1 (3x3) -> h12 f32 ; residual proj (1x1, padded in) -> resid f32
  conv_kernel<9, 1, 0><<<ggrid, 256, 0, stream>>>(xp, w1p, c1b, h12, nullptr,
                                                  nullptr, nullptr, nullptr, nullptr, nullptr, nullptr);
  conv_kernel<1, 1, 0><<<ggrid, 256, 0, stream>>>(xp, wrp, rpb, resid, nullptr,
                                                  nullptr, nullptr, nullptr, nullptr, nullptr, nullptr);
  // gn1 + silu -> h1p (padded bf16)
  gn_kernel<0><<<dim3(NGROUP, NB), 256, 0, stream>>>(h12, g1w, g1b, nullptr, nullptr, nullptr, h1p);
  // conv2 (3x3) -> h12 f32
  conv_kernel<9, 1, 0><<<ggrid, 256, 0, stream>>>(h1p, w2p, c2b, h12, nullptr,
                                                  nullptr, nullptr, nullptr, nullptr, nullptr, nullptr);
  // gn2 * (1+cond) + resid -> h12 (in-place f32), hb bf16
  gn_kernel<1><<<dim3(NGROUP, NB), 256, 0, stream>>>(h12, g2w, g2b, cndv, resid, h12, hb);
  // fused q/k/vT (1x1)
  conv_kernel<1, 0, 5><<<qgrid, 256, 0, stream>>>(hb, wqkv, nullptr, nullptr, nullptr,
                                                  qbuf, kbuf, vTb, qb, kb, vb);
  // attention -> aob bf16 NHWC
  attn_kernel<<<512, 256, 0, stream>>>(qbuf, kbuf, vTb, aob);
  // out proj + bias + h -> d_out NCHW f32 directly
  conv_kernel<1, 0, 2><<<ggrid, 256, 0, stream>>>(aob, wop, ob, out, h12,
                                                  nullptr, nullptr, nullptr, nullptr, nullptr, nullptr);
}